// Round 3
// baseline (2190.199 us; speedup 1.0000x reference)
//
#include <hip/hip_runtime.h>
#include <hip/hip_bf16.h>

typedef unsigned short u16;   // bf16 bits
typedef __attribute__((ext_vector_type(8))) short bf16x8;   // MFMA A/B frag
typedef __attribute__((ext_vector_type(4))) float f32x4;    // MFMA C/D frag

#define B_   32
#define N_   1024
#define E_   16384
#define ET_  17408            // E_ + N_ self-loops
#define IN_DIM 768
#define HID  512
#define OUT_ 400
#define PAIR_ 800
#define UVW_ 1600             // U(800) ++ V(800) per node
#define FEAT_ELEMS 13107200   // B_*N_*OUT_
#define MAXD 128

__device__ __forceinline__ float u2f(u16 u) {
    union { unsigned int i; float f; } v; v.i = ((unsigned int)u) << 16; return v.f;
}
__device__ __forceinline__ u16 f2u(float f) {
    __hip_bfloat16 h = __float2bfloat16(f);   // RNE, HW cvt on gfx950
    return *(u16*)&h;
}
__device__ __forceinline__ unsigned int pack2(float a, float b) {
    return (unsigned int)f2u(a) | ((unsigned int)f2u(b) << 16);
}

__device__ __forceinline__ float gelu_f(float x) {
    const float c = 0.7978845608028654f;          // sqrt(2/pi)
    float u = c * (x + 0.044715f * x * x * x);
    float t = 2.0f / (1.0f + __expf(-2.0f * u)) - 1.0f;   // tanh(u), overflow-safe
    return 0.5f * x * (1.0f + t);
}

// async global->LDS, 16 B per lane; LDS dest is wave-uniform base + lane*16
__device__ __forceinline__ void load_lds16(const void* g, void* l) {
    __builtin_amdgcn_global_load_lds(
        (const __attribute__((address_space(1))) void*)g,
        (__attribute__((address_space(3))) void*)l, 16, 0, 0);
}

// ---------------------------------------------------------------------------
// Weight transpose + bf16 convert: Wt[n][k] = bf16(W[k][n]). Tiny, once/launch.
// ---------------------------------------------------------------------------
__global__ void wt_k(const float* __restrict__ W, u16* __restrict__ Wt,
                     int K, int N)
{
    int i = blockIdx.x * 256 + threadIdx.x;
    if (i >= N * K) return;
    int n = i / K, k = i - n * K;
    Wt[i] = f2u(W[(size_t)k * N + n]);
}

// h_w1 [800][800] -> uvwt [1600][400] bf16 (transposed, halves split):
//   n <  800: uvwt[n][k]   = h_w1[k][n]          (U = feat @ h_w1[0:400,:])
//   n >= 800: uvwt[n][k]   = h_w1[400+k][n-800]  (V = feat @ h_w1[400:800,:])
__global__ void wtuv_k(const float* __restrict__ W, u16* __restrict__ Wt)
{
    int i = blockIdx.x * 256 + threadIdx.x;       // over 1600*400
    if (i >= UVW_ * OUT_) return;
    int n = i / OUT_, k = i - n * OUT_;
    int row = (n >= PAIR_) ? OUT_ + k : k;
    int col = (n >= PAIR_) ? n - PAIR_ : n;
    Wt[i] = f2u(W[(size_t)row * PAIR_ + col]);
}

// f32 -> bf16 bulk convert, 8 elems/lane
__global__ void f2b_k(const float* __restrict__ X, u16* __restrict__ Y, int n8)
{
    int i = blockIdx.x * 256 + threadIdx.x;
    if (i >= n8) return;
    const float4* p = (const float4*)X + (size_t)i * 2;
    float4 a = p[0], b = p[1];
    uint4 o;
    o.x = pack2(a.x, a.y); o.y = pack2(a.z, a.w);
    o.z = pack2(b.x, b.y); o.w = pack2(b.z, b.w);
    ((uint4*)Y)[i] = o;
}

// ---------------------------------------------------------------------------
// MFMA GEMM: C[M,N] = act(A[M,K] @ W[K,N] + bias), f32 accumulate.
// Tile 128x128, BK=64; 4 waves, each 64x64 via 4x4 grid of 16x16x32 MFMAs.
// Wt pre-transposed bf16 [N][K].
// ASRC: 0 = f32 A (VGPR cvt staging); 1 = bf16 A (async global_load_lds).
// T1 XCD-chunked bijective swizzle (m204): co-locate a row-tile's col-tiles
// on one XCD so the A panel is fetched into that XCD's L2 once.
// FUSE_H3: skip the C store; instead contract the in-register p2 tile with
// w3 [N][3] (gelu applied first), shfl-reduce over lm lanes, atomicAdd 3
// floats/row into outp[(row_base+row)*3]. b3 added once (bn==0 wave wn==0).
// Garbage cols >= N contribute 0 (acc=0 via zbuf, w3/bias masked to 0).
// LDS layout: unpadded pitch 128 B, XOR swizzle phys_chunk = log_chunk^(row&7)
// (16B chunks) -> global_load_lds lane-contiguity satisfied AND quarter-wave
// ds_read_b128 is uniform 2-way on banks (free, m136). OOB lanes read zbuf.
// ---------------------------------------------------------------------------
template<int ASRC, bool DO_GELU, bool HAS_BIAS, bool OUT_F32, bool FUSE_H3>
__global__ __launch_bounds__(256)
void mfma_gemm_k(const float* __restrict__ Af, const u16* __restrict__ Ab,
                 const u16* __restrict__ Wt, const float* __restrict__ bias,
                 u16* __restrict__ Cb, float* __restrict__ Cf,
                 int M, int N, int K,
                 const u16* __restrict__ zbuf,
                 const float* __restrict__ w3p, const float* __restrict__ b3p,
                 float* __restrict__ outp, int row_base)
{
    __shared__ __align__(16) u16 As[128 * 64];
    __shared__ __align__(16) u16 Bs[128 * 64];
    const int tid  = threadIdx.x;
    // --- T1 bijective XCD swizzle ---
    const int gx   = gridDim.x;
    const int nwg  = gx * gridDim.y;
    const int orig = blockIdx.y * gx + blockIdx.x;
    const int qc   = nwg >> 3, rc = nwg & 7;
    const int xcd  = orig & 7, lid = orig >> 3;
    const int wg   = ((xcd < rc) ? xcd * (qc + 1) : rc * (qc + 1) + (xcd - rc) * qc) + lid;
    const int bm   = (wg / gx) * 128;
    const int bn   = (wg % gx) * 128;
    const int wave = tid >> 6;
    const int lane = tid & 63;
    const int wm   = (wave >> 1) * 64;
    const int wn   = (wave & 1) * 64;
    const int lm   = lane & 15;
    const int lq   = lane >> 4;
    const int lb   = lm & 7;
    // async-staging lane geometry: instr c4 covers rows w*32+c4*8 .. +7
    const int l8 = lane >> 3;            // row within 8-row group
    const int cl = (lane & 7) ^ l8;      // logical 8-elem chunk for this lane

    // per-c4 row metadata
    size_t arow[4]; size_t brow[4]; bool bok[4];
    #pragma unroll
    for (int c4 = 0; c4 < 4; ++c4) {
        int rt = wave * 32 + c4 * 8 + l8;          // tile row 0..127
        if (ASRC == 1) arow[c4] = (size_t)(bm + rt) * K;
        int n = bn + rt;
        bok[c4] = (n < N);
        brow[c4] = (size_t)(n < N ? n : 0) * K;
    }
    // VGPR-staging geometry (ASRC 0)
    const int vrow = tid >> 1, vhalf = tid & 1;

    f32x4 acc[4][4] = {};

    for (int k0 = 0; k0 < K; k0 += 64) {
        // ---- stage A
        if (ASRC == 1) {
            int kk = k0 + cl * 8;
            #pragma unroll
            for (int c4 = 0; c4 < 4; ++c4) {
                const u16* ga = (kk < K) ? Ab + arow[c4] + kk : zbuf;
                load_lds16(ga, (char*)As + (wave * 32 + c4 * 8) * 128);
            }
        } else {
            #pragma unroll
            for (int c = 0; c < 4; ++c) {
                int c_log = vhalf * 4 + c;
                int kk = k0 + c_log * 8;
                uint4 wv = make_uint4(0, 0, 0, 0);
                if (kk < K) {
                    const float* p = Af + (size_t)(bm + vrow) * K + kk;
                    float4 v0 = *(const float4*)p;
                    float4 v1 = *(const float4*)(p + 4);
                    wv.x = pack2(v0.x, v0.y); wv.y = pack2(v0.z, v0.w);
                    wv.z = pack2(v1.x, v1.y); wv.w = pack2(v1.z, v1.w);
                }
                int pc = c_log ^ (vrow & 7);
                *(uint4*)((char*)As + vrow * 128 + pc * 16) = wv;
            }
        }
        // ---- stage B (always async; Wt bf16 [N][K])
        {
            int kk = k0 + cl * 8;
            #pragma unroll
            for (int c4 = 0; c4 < 4; ++c4) {
                const u16* gb = (bok[c4] && kk < K) ? Wt + brow[c4] + kk : zbuf;
                load_lds16(gb, (char*)Bs + (wave * 32 + c4 * 8) * 128);
            }
        }
        __syncthreads();
        #pragma unroll
        for (int kh = 0; kh < 2; ++kh) {
            bf16x8 af[4], bfr[4];
            #pragma unroll
            for (int t = 0; t < 4; ++t)
                af[t] = *(const bf16x8*)((const char*)As +
                        (wm + t * 16 + lm) * 128 + (((kh * 4 + lq) ^ lb) * 16));
            #pragma unroll
            for (int u = 0; u < 4; ++u)
                bfr[u] = *(const bf16x8*)((const char*)Bs +
                        (wn + u * 16 + lm) * 128 + (((kh * 4 + lq) ^ lb) * 16));
            #pragma unroll
            for (int t = 0; t < 4; ++t)
                #pragma unroll
                for (int u = 0; u < 4; ++u)
                    acc[t][u] = __builtin_amdgcn_mfma_f32_16x16x32_bf16(
                        af[t], bfr[u], acc[t][u], 0, 0, 0);
        }
        __syncthreads();
    }

    // ---- fused head3 epilogue: pred += gelu(p2_tile) @ w3 (no p2 store)
    if (FUSE_H3) {
        float w3c[4][3]; float bvv[4];
        #pragma unroll
        for (int u = 0; u < 4; ++u) {
            int col = bn + wn + u * 16 + lm;
            bool ok = (col < N);
            bvv[u]    = ok ? bias[col] : 0.f;
            w3c[u][0] = ok ? w3p[col * 3 + 0] : 0.f;
            w3c[u][1] = ok ? w3p[col * 3 + 1] : 0.f;
            w3c[u][2] = ok ? w3p[col * 3 + 2] : 0.f;
        }
        #pragma unroll
        for (int t = 0; t < 4; ++t) {
            #pragma unroll
            for (int r = 0; r < 4; ++r) {
                float s0 = 0.f, s1 = 0.f, s2 = 0.f;
                #pragma unroll
                for (int u = 0; u < 4; ++u) {
                    float v = gelu_f(acc[t][u][r] + bvv[u]);
                    s0 += v * w3c[u][0];
                    s1 += v * w3c[u][1];
                    s2 += v * w3c[u][2];
                }
                #pragma unroll
                for (int off = 8; off; off >>= 1) {
                    s0 += __shfl_xor(s0, off);
                    s1 += __shfl_xor(s1, off);
                    s2 += __shfl_xor(s2, off);
                }
                if (lm == 0) {
                    int rowg = bm + wm + t * 16 + lq * 4 + r;
                    if (bn == 0 && wn == 0) { s0 += b3p[0]; s1 += b3p[1]; s2 += b3p[2]; }
                    float* dst = outp + (size_t)(row_base + rowg) * 3;
                    atomicAdd(dst + 0, s0);
                    atomicAdd(dst + 1, s1);
                    atomicAdd(dst + 2, s2);
                }
            }
        }
        return;
    }

    // ---- epilogue: C col = lane&15, row = quad*4 + reg (verified m89/m91)
    #pragma unroll
    for (int u = 0; u < 4; ++u) {
        int col = bn + wn + u * 16 + lm;
        if (col >= N) continue;
        float bv = HAS_BIAS ? bias[col] : 0.f;
        #pragma unroll
        for (int t = 0; t < 4; ++t) {
            #pragma unroll
            for (int r = 0; r < 4; ++r) {
                int rowg = bm + wm + t * 16 + lq * 4 + r;
                float v = acc[t][u][r] + bv;
                if (DO_GELU) v = gelu_f(v);
                if (OUT_F32) {
                    Cf[(size_t)rowg * N + col] = v;
                    if (Cb) Cb[(size_t)rowg * N + col] = f2u(v);  // dual write
                } else {
                    Cb[(size_t)rowg * N + col] = f2u(v);
                }
            }
        }
    }
}

// ---------------------------------------------------------------------------
// Pair fuse: p1[r,:] = gelu(U[src] + V[dst] + b1)  (distributed head GEMM1).
// UV bf16 [nodes][1600] = [U(800) | V(800)]. Flattened: 1 thread = one 8-elem
// chunk (row = idx/100 via magic div); no idle lanes. UV rows L3-resident.
// ---------------------------------------------------------------------------
__global__ __launch_bounds__(256)
void pair_fuse_k(const u16* __restrict__ UV, const float* __restrict__ b1,
                 const int* __restrict__ src0, const int* __restrict__ dst0,
                 u16* __restrict__ p1, int b0, int nrows)
{
    unsigned idx = blockIdx.x * 256u + threadIdx.x;
    unsigned total = (unsigned)nrows * 100u;
    if (idx >= total) return;
    unsigned r  = (unsigned)(((unsigned long long)idx * 1374389535ull) >> 37); // /100
    unsigned c8 = idx - r * 100u;
    int e = r & (E_ - 1);
    int gs, gd;
    if (b0 >= 0) {                        // big mode: global node ids
        int b = b0 + (int)(r >> 14);
        gs = (b << 10) + src0[e];
        gd = (b << 10) + dst0[e];
    } else {                              // small mode: per-batch UV table
        gs = src0[e]; gd = dst0[e];
    }
    uint4 qu = *(const uint4*)(UV + (size_t)gs * UVW_ + c8 * 8);
    uint4 qv = *(const uint4*)(UV + (size_t)gd * UVW_ + PAIR_ + c8 * 8);
    float4 bva = *(const float4*)(b1 + c8 * 8);
    float4 bvb = *(const float4*)(b1 + c8 * 8 + 4);
    float bb[8] = {bva.x, bva.y, bva.z, bva.w, bvb.x, bvb.y, bvb.z, bvb.w};
    unsigned int uu[4] = {qu.x, qu.y, qu.z, qu.w};
    unsigned int vv[4] = {qv.x, qv.y, qv.z, qv.w};
    uint4 o; unsigned int* op = (unsigned int*)&o;
    #pragma unroll
    for (int q = 0; q < 4; ++q) {
        float a0 = u2f((u16)(uu[q] & 0xffff)) + u2f((u16)(vv[q] & 0xffff)) + bb[2*q];
        float a1 = u2f((u16)(uu[q] >> 16))    + u2f((u16)(vv[q] >> 16))    + bb[2*q+1];
        op[q] = pack2(gelu_f(a0), gelu_f(a1));
    }
    *(uint4*)(p1 + (size_t)r * PAIR_ + c8 * 8) = o;
}

// ---------------------------------------------------------------------------
// Attention scores: a_s[n,h] = sum_f wh[n,h*200+f]*att_src[h*200+f]; same a_d.
// ---------------------------------------------------------------------------
__global__ __launch_bounds__(256)
void scores_k(const u16* __restrict__ wh, const float* __restrict__ att_s,
              const float* __restrict__ att_d, float* __restrict__ a_s,
              float* __restrict__ a_d)
{
    int n = blockIdx.x * 4 + (threadIdx.x >> 6);
    int lane = threadIdx.x & 63;
    const u16* row = wh + (size_t)n * OUT_;
    float as0 = 0, as1 = 0, ad0 = 0, ad1 = 0;
    for (int f = lane; f < OUT_; f += 64) {
        float v = u2f(row[f]);
        float s = att_s[f];
        float d = att_d[f];
        if (f < 200) { as0 += v * s; ad0 += v * d; }
        else         { as1 += v * s; ad1 += v * d; }
    }
    for (int off = 32; off; off >>= 1) {
        as0 += __shfl_xor(as0, off); as1 += __shfl_xor(as1, off);
        ad0 += __shfl_xor(ad0, off); ad1 += __shfl_xor(ad1, off);
    }
    if (lane == 0) {
        a_s[(size_t)n * 2 + 0] = as0; a_s[(size_t)n * 2 + 1] = as1;
        a_d[(size_t)n * 2 + 0] = ad0; a_d[(size_t)n * 2 + 1] = ad1;
    }
}

// ---------------------------------------------------------------------------
// CSR build (edges shared across batches; incl. self-loops)
// ---------------------------------------------------------------------------
__global__ void csr_count_k(const int* __restrict__ edges, int* __restrict__ deg)
{
    int et = blockIdx.x * blockDim.x + threadIdx.x;
    if (et >= ET_) return;
    int dst = (et < E_) ? edges[E_ + et] : (et - E_);
    atomicAdd(&deg[dst], 1);
}

__global__ __launch_bounds__(1024)
void csr_scan_k(const int* __restrict__ deg, int* __restrict__ row_ptr,
                int* __restrict__ cnt)
{
    __shared__ int s[1024];
    int t = threadIdx.x;
    int d = deg[t];
    s[t] = d;
    __syncthreads();
    for (int off = 1; off < 1024; off <<= 1) {
        int v = (t >= off) ? s[t - off] : 0;
        __syncthreads();
        s[t] += v;
        __syncthreads();
    }
    row_ptr[t] = s[t] - d;   // exclusive
    cnt[t] = s[t] - d;
    if (t == 1023) row_ptr[1024] = s[t];
}

__global__ void csr_fill_k(const int* __restrict__ edges, int* __restrict__ cnt,
                           int* __restrict__ col_src)
{
    int et = blockIdx.x * blockDim.x + threadIdx.x;
    if (et >= ET_) return;
    int src, dst;
    if (et < E_) { src = edges[et]; dst = edges[E_ + et]; }
    else         { src = et - E_;  dst = src; }
    int pos = atomicAdd(&cnt[dst], 1);
    col_src[pos] = src;
}

// ---------------------------------------------------------------------------
// Fused GAT softmax + aggregation + residual, in place on f32 feat (d_out).
// Vectorized: lane<50 handles 8 contiguous cols via uint4 wh loads; 4 j-slices
// (one per wave) reduced through padded LDS partials. Optionally emits bf16
// copy of feat (featb16) for the UV GEMM.
// ---------------------------------------------------------------------------
__global__ __launch_bounds__(256)
void gat_k(const u16* __restrict__ wh,
           const float* __restrict__ a_s, const float* __restrict__ a_d,
           const int* __restrict__ row_ptr, const int* __restrict__ col_src,
           const float* __restrict__ gat_b, float* __restrict__ feat,
           u16* __restrict__ featb16)
{
    int gn = blockIdx.x;                  // b*1024 + n
    int b = gn >> 10, n = gn & 1023;
    int tid = threadIdx.x;
    __shared__ float s_ee[2][MAXD];
    __shared__ int   s_src[MAXD];
    __shared__ float s_misc[6];           // m0,m1,invz0,invz1,ad0,ad1
    __shared__ float s_part[4][50][9];    // +1 pad col: spread banks
    int start = row_ptr[n];
    int deg = row_ptr[n + 1] - start;

    if (tid < 64) {
        int lane = tid;
        float ad0 = a_d[(size_t)gn * 2 + 0];
        float ad1 = a_d[(size_t)gn * 2 + 1];
        float m0 = -1e30f, m1 = -1e30f;
        for (int j = lane; j < deg; j += 64) {
            int gs = (b << 10) + col_src[start + j];
            float e0 = a_s[(size_t)gs * 2 + 0] + ad0; e0 = (e0 > 0.f) ? e0 : 0.2f * e0;
            float e1 = a_s[(size_t)gs * 2 + 1] + ad1; e1 = (e1 > 0.f) ? e1 : 0.2f * e1;
            if (j < MAXD) { s_ee[0][j] = e0; s_ee[1][j] = e1; s_src[j] = gs; }
            m0 = fmaxf(m0, e0); m1 = fmaxf(m1, e1);
        }
        for (int off = 32; off; off >>= 1) {
            m0 = fmaxf(m0, __shfl_xor(m0, off));
            m1 = fmaxf(m1, __shfl_xor(m1, off));
        }
        float z0 = 0.f, z1 = 0.f;
        for (int j = lane; j < deg; j += 64) {
            float e0, e1;
            if (j < MAXD) { e0 = s_ee[0][j]; e1 = s_ee[1][j]; }
            else {
                int gs = (b << 10) + col_src[start + j];
                e0 = a_s[(size_t)gs * 2 + 0] + ad0; e0 = (e0 > 0.f) ? e0 : 0.2f * e0;
                e1 = a_s[(size_t)gs * 2 + 1] + ad1; e1 = (e1 > 0.f) ? e1 : 0.2f * e1;
            }
            float t0 = __expf(e0 - m0), t1 = __expf(e1 - m1);
            if (j < MAXD) { s_ee[0][j] = t0; s_ee[1][j] = t1; }
            z0 += t0; z1 += t1;
        }
        for (int off = 32; off; off >>= 1) {
            z0 += __shfl_xor(z0, off);
            z1 += __shfl_xor(z1, off);
        }
        if (lane == 0) {
            s_misc[0] = m0; s_misc[1] = m1;
            s_misc[2] = (z0 > 0.f) ? 1.f / z0 : 0.f;
            s_misc[3] = (z1 > 0.f) ? 1.f / z1 : 0.f;
            s_misc[4] = ad0; s_misc[5] = ad1;
        }
    }
    __syncthreads();

    int wv = tid >> 6, ln = tid & 63;
    if (ln < 50) {
        int h = (ln >= 25);
        float m = s_misc[h], ad = s_misc[4 + h];
        float acc[8] = {};
        for (int j = wv; j < deg; j += 4) {
            float w; int gs;
            if (j < MAXD) { w = s_ee[h][j]; gs = s_src[j]; }
            else {
                gs = (b << 10) + col_src[start + j];
                float e = a_s[(size_t)gs * 2 + h] + ad;
                e = (e > 0.f) ? e : 0.2f * e;
                w = __expf(e - m);
            }
            uint4 q = *(const uint4*)(wh + (size_t)gs * OUT_ + ln * 8);
            acc[0] += w * u2f((u16)(q.x & 0xffff));
            acc[1] += w * u2f((u16)(q.x >> 16));
            acc[2] += w * u2f((u16)(q.y & 0xffff));
            acc[3] += w * u2f((u16)(q.y >> 16));
            acc[4] += w * u2f((u16)(q.z & 0xffff));
            acc[5] += w * u2f((u16)(q.z >> 16));
            acc[6] += w * u2f((u16)(q.w & 0xffff));
            acc[7] += w * u2f((u16)(q.w >> 16));
        }
        #pragma unroll
        for (int k = 0; k < 8; ++k) s_part[wv][ln][k] = acc[k];
    }
    __syncthreads();
    if (tid < 50) {
        int h = (tid >= 25);
        float iz = s_misc[2 + h];
        size_t base = (size_t)gn * OUT_ + tid * 8;
        float4 f0 = *(const float4*)(feat + base);
        float4 f1 = *(const float4*)(feat + base + 4);
        float fv[8] = { f0.x, f0.y, f0.z, f0.w, f1.x, f1.y, f1.z, f1.w };
        float o[8];
        #pragma unroll
        for (int k = 0; k < 8; ++k) {
            float s = s_part[0][tid][k] + s_part[1][tid][k] +
                      s_part[2][tid][k] + s_part[3][tid][k];
            o[k] = fv[k] + s * iz + gat_b[tid * 8 + k];
        }
        *(float4*)(feat + base)     = make_float4(o[0], o[1], o[2], o[3]);
        *(float4*)(feat + base + 4) = make_float4(o[4], o[5], o[6], o[7]);
        if (featb16) {
            uint4 bq;
            bq.x = pack2(o[0], o[1]); bq.y = pack2(o[2], o[3]);
            bq.z = pack2(o[4], o[5]); bq.w = pack2(o[6], o[7]);
            *(uint4*)(featb16 + base) = bq;
        }
    }
}

// ---------------------------------------------------------------------------
// Final tiny GEMM (small-mode only): pred[e,:] = p2[e,:] @ w3[400,3] + b3.
// ---------------------------------------------------------------------------
__global__ __launch_bounds__(256)
void head3_k(const u16* __restrict__ p2, const float* __restrict__ w3,
             const float* __restrict__ b3, float* __restrict__ out,
             int row_base, int nrows)
{
    int wv = threadIdx.x >> 6, lane = threadIdx.x & 63;
    float w3r[24];
    if (lane < 50) {
        #pragma unroll
        for (int q = 0; q < 6; ++q) {
            float4 v = *(const float4*)(w3 + lane * 24 + q * 4);
            w3r[q * 4 + 0] = v.x; w3r[q * 4 + 1] = v.y;
            w3r[q * 4 + 2] = v.z; w3r[q * 4 + 3] = v.w;
        }
    }
    int e0 = blockIdx.x * 16 + wv * 4;
    for (int ei = 0; ei < 4; ++ei) {
        int e = e0 + ei;
        if (e >= nrows) break;
        float s0 = 0, s1 = 0, s2 = 0;
        if (lane < 50) {
            uint4 q = *(const uint4*)(p2 + (size_t)e * OUT_ + lane * 8);
            float f[8];
            f[0] = u2f((u16)(q.x & 0xffff)); f[1] = u2f((u16)(q.x >> 16));
            f[2] = u2f((u16)(q.y & 0xffff)); f[3] = u2f((u16)(q.y >> 16));
            f[4] = u2f((u16)(q.z & 0xffff)); f[5] = u2f((u16)(q.z >> 16));
            f[6] = u2f((u16)(q.w & 0xffff)); f[7] = u2f((u16)(q.w >> 16));
            #pragma unroll
            for (int k = 0; k < 8; ++k) {
                s0 += f[k] * w3r[k * 3 + 0];
                s1 += f[k] * w3r[k * 3 + 1];
                s2 += f[k] * w3r[k * 3 + 2];
            }
        }
        for (int off = 32; off; off >>= 1) {
            s0 += __shfl_xor(s0, off);
            s1 += __shfl_xor(s1, off);
            s2 += __shfl_xor(s2, off);
        }
        if (lane == 0) {
            size_t o = (size_t)FEAT_ELEMS + (size_t)(row_base + e) * 3;
            out[o + 0] = s0 + b3[0];
            out[o + 1] = s1 + b3[1];
            out[o + 2] = s2 + b3[2];
        }
    }
}

extern "C" void kernel_launch(void* const* d_in, const int* in_sizes, int n_in,
                              void* d_out, int out_size, void* d_ws, size_t ws_size,
                              hipStream_t stream)
{
    const float* patch  = (const float*)d_in[0];
    const int*   edges  = (const int*)d_in[1];
    const float* enc_w1 = (const float*)d_in[2];
    const float* enc_b1 = (const float*)d_in[3];
    const float* enc_w2 = (const float*)d_in[4];
    const float* enc_b2 = (const float*)d_in[5];
    const float* gat_w  = (const float*)d_in[6];
    const float* att_s  = (const float*)d_in[7];
    const float* att_d  = (const float*)d_in[8];
    const float* gat_b  = (const float*)d_in[9];
    const float* h_w1   = (const float*)d_in[10];
    const float* h_b1   = (const float*)d_in[11];
    const float* h_w2   = (const float*)d_in[12];
    const float* h_b2   = (const float*)d_in[13];
    const float* h_w3   = (const float*)d_in[14];
    const float* h_b3   = (const float*)d_in[15];
    float* out  = (float*)d_out;
    float* feat = out;                          // f32 [32768,400] in d_out
    char*  ws   = (char*)d_ws;

    const int* src0 = edges;
    const int* dst0 = edges + E_;

    // --- mode select from ws_size (deterministic; graph-capture safe) ------
    // big-mode layout:
    //   [0,R0)                enc1 bf16 (33.5MB); featb16 overlays (dead enc1)
    //   [R0, R0+26.2MB)       whb bf16            (dead after gat_k)
    //   [R0+26.2, R0+52.4MB)  encb16 bf16 (enc out, consumed by GAT linear)
    //   [R0, R0+UVSZ)         UV bf16 [32768,1600] (overlays whb+encb16, after)
    //   [R0+UVSZ, +CB*26.2MB) p1 chunk; patchb16 (50.3MB) overlays p1 early
    //   [ws_size-TAIL, ..)    weights + scores + CSR + zbuf
    // p2 eliminated (head3 fused into GEMM2 epilogue via atomics).
    // CB=4 keeps UV(105MB)+p1(105MB) L3-resident; CB>=2 needed for patchb16.
    const size_t R0 = 33554432ull, TAIL = 4194304ull;
    const size_t UVSZ = 104857600ull;           // 32768*1600*2
    const size_t P1SZ = 26214400ull;            // per-batch p1
    int CB = 0;
    if      (ws_size >= R0 + UVSZ + TAIL + 4 * P1SZ) CB = 4;
    else if (ws_size >= R0 + UVSZ + TAIL + 2 * P1SZ) CB = 2;
    const bool big = (CB >= 2);

    u16 *enc1, *whb, *p1, *p2, *featb16, *uv, *w1t, *w2t, *gwt, *uvwt, *hw2t;
    u16 *patchb16, *encb16;
    float *a_s, *a_d; int *deg;
    if (big) {
        enc1    = (u16*)ws;
        featb16 = (u16*)ws;                     // overlays enc1 (dead)
        whb     = (u16*)(ws + R0);
        uv      = (u16*)(ws + R0);              // overlays whb (dead after gat)
        encb16  = (u16*)(ws + R0 + 26214400ull);// enc bf16, dead before UV GEMM
        p1      = (u16*)(ws + R0 + UVSZ);
        patchb16= (u16*)(ws + R0 + UVSZ);       // overlays p1 (dead before head)
        p2      = nullptr;
        size_t tb = (ws_size - TAIL) & ~(size_t)255;
        w1t  = (u16*)(ws + tb);
        w2t  = (u16*)(ws + tb + 786432);
        gwt  = (u16*)(ws + tb + 1196032);
        uvwt = (u16*)(ws + tb + 1516032);       // 1600*400*2 = 1,280,000
        hw2t = (u16*)(ws + tb + 2796032);
        a_s  = (float*)(ws + tb + 3436032);
        a_d  = (float*)(ws + tb + 3698176);
        deg  = (int*)(ws + tb + 3960320);
    } else {
        // small mode: per-batch loop; UV table is per-batch [1024,1600] bf16
        enc1    = (u16*)ws;                     // sequenced overlays
        whb     = (u16*)ws;
        p1      = (u16*)ws;
        featb16 = nullptr;
        patchb16= nullptr;
        encb16  = nullptr;
        p2      = (u16*)(ws + 26214400);
        uv      = (u16*)(ws + 39321600);        // 1024*1600*2 = 3,276,800
        w1t  = (u16*)(ws + 42598400);
        w2t  = (u16*)(ws + 43384832);
        gwt  = (u16*)(ws + 43794432);
        uvwt = (u16*)(ws + 44114432);
        hw2t = (u16*)(ws + 45394432);
        a_s  = (float*)(ws + 46034432);
        a_d  = (float*)(ws + 46296576);
        deg  = (int*)(ws + 46558720);
    }
    int* row_ptr = deg + 1024;
    int* cnt     = row_ptr + 1032;
    int* col_src = cnt + 1024;
    u16* zbuf = (u16*)(col_src + 17408);        // 256 B zero scratch (16B aligned)

    hipMemsetAsync(zbuf, 0, 256, stream);
    if (big)  // zero pred region for atomic accumulation
        hipMemsetAsync(out + FEAT_ELEMS, 0, (size_t)B_ * E_ * 3 * sizeof(float), stream);

    // weight transposes (bf16), tiny
    wt_k<<<(HID * IN_DIM + 255) / 256, 256, 0, stream>>>(enc_w1, w1t, IN_DIM, HID);
    wt_k<<<(OUT_ * HID + 255) / 256, 256, 0, stream>>>(enc_w2, w2t, HID, OUT_);
    wt_k<<<(OUT_ * OUT_ + 255) / 256, 256, 0, stream>>>(gat_w, gwt, OUT_, OUT_);
    wtuv_k<<<(UVW_ * OUT_ + 255) / 256, 256, 0, stream>>>(h_w1, uvwt);
    wt_k<<<(OUT_ * PAIR_ + 255) / 256, 256, 0, stream>>>(h_w2, hw2t, PAIR_, OUT_);

    // CSR by dst (batch-independent)
    hipMemsetAsync(deg, 0, 1024 * sizeof(int), stream);
    csr_count_k<<<(ET_ + 255) / 256, 256, 0, stream>>>(edges, deg);
    csr_scan_k<<<1, 1024, 0, stream>>>(deg, row_ptr, cnt);
    csr_fill_k<<<(ET_ + 255) / 256, 256, 0, stream>>>(edges, cnt, col_src);

    if (big) {
        // patch -> bf16 once (numerics identical: staging already cvt'd)
        f2b_k<<<(B_ * N_ * IN_DIM / 8 + 255) / 256, 256, 0, stream>>>(
            patch, patchb16, B_ * N_ * IN_DIM / 8);
        // encoder: enc1 = gelu(patch @ w1 + b1)
        mfma_gemm_k<1, true, true, false, false><<<dim3(HID / 128, (B_ * N_) / 128), 256, 0, stream>>>(
            nullptr, patchb16, w1t, enc_b1, enc1, nullptr, B_ * N_, HID, IN_DIM, zbuf,
            nullptr, nullptr, nullptr, 0);
        // feat(f32, d_out) + encb16(bf16) = enc1 @ w2 + b2
        mfma_gemm_k<1, false, true, true, false><<<dim3((OUT_ + 127) / 128, (B_ * N_) / 128), 256, 0, stream>>>(
            nullptr, enc1, w2t, enc_b2, encb16, feat, B_ * N_, OUT_, HID, zbuf,
            nullptr, nullptr, nullptr, 0);
        // GAT linear: wh = enc(bf16) @ gat_w
        mfma_gemm_k<1, false, false, false, false><<<dim3((OUT_ + 127) / 128, (B_ * N_) / 128), 256, 0, stream>>>(
            nullptr, encb16, gwt, nullptr, whb, nullptr, B_ * N_, OUT_, OUT_, zbuf,
            nullptr, nullptr, nullptr, 0);
    } else {
        mfma_gemm_k<0, true, true, false, false><<<dim3(HID / 128, (B_ * N_) / 128), 256, 0, stream>>>(
            patch, nullptr, w1t, enc_b1, enc1, nullptr, B_ * N_, HID, IN_DIM, zbuf,
            nullptr, nullptr, nullptr, 0);
        mfma_gemm_k<1, false, true, true, false><<<dim3((OUT_ + 127) / 128, (B_ * N_) / 128), 256, 0, stream>>>(
            nullptr, enc1, w2t, enc_b2, nullptr, feat, B_ * N_, OUT_, HID, zbuf,
            nullptr, nullptr, nullptr, 0);
        mfma_gemm_k<0, false, false, false, false><<<dim3((OUT_ + 127) / 128, (B_ * N_) / 128), 256, 0, stream>>>(
            feat, nullptr, gwt, nullptr, whb, nullptr, B_ * N_, OUT_, OUT_, zbuf,
            nullptr, nullptr, nullptr, 0);
    }

    scores_k<<<(B_ * N_) / 4, 256, 0, stream>>>(whb, att_s, att_d, a_s, a_d);
    gat_k<<<B_ * N_, 256, 0, stream>>>(whb, a_s, a_d, row_ptr, col_src,
                                       gat_b, feat, featb16);

    // predict head — head GEMM1 distributed over the pair-gather:
    //   pair @ h_w1 = feat[src] @ h_w1[0:400,:] + feat[dst] @ h_w1[400:800,:]
    //              = U[src] + V[dst]   (per-NODE GEMM: 32x less FLOP)
    // GEMM2's epilogue contracts p2 (in registers) with w3 -> pred atomics.
    if (big) {
        // UV = featb16 @ uvwt  -> bf16 [32768,1600]
        mfma_gemm_k<1, false, false, false, false><<<dim3((UVW_ + 127) / 128, (B_ * N_) / 128), 256, 0, stream>>>(
            nullptr, featb16, uvwt, nullptr, uv, nullptr, B_ * N_, UVW_, OUT_, zbuf,
            nullptr, nullptr, nullptr, 0);
        for (int b0 = 0; b0 < B_; b0 += CB) {
            int Mr = CB * E_;
            pair_fuse_k<<<(Mr * 100 + 255) / 256, 256, 0, stream>>>(
                uv, h_b1, src0, dst0, p1, b0, Mr);
            mfma_gemm_k<1, true, true, false, true><<<dim3((OUT_ + 127) / 128, Mr / 128), 256, 0, stream>>>(
                nullptr, p1, hw2t, h_b2, nullptr, nullptr, Mr, OUT_, PAIR_, zbuf,
                h_w3, h_b3, out + FEAT_ELEMS, b0 * E_);
        }
    } else {
        for (int b = 0; b < B_; ++b) {
            const float* featb = feat + (size_t)b * N_ * OUT_;
            mfma_gemm_k<0, false, false, false, false><<<dim3((UVW_ + 127) / 128, N_ / 128), 256, 0, stream>>>(
                featb, nullptr, uvwt, nullptr, uv, nullptr, N_, UVW_, OUT_, zbuf,
                nullptr, nullptr, nullptr, 0);
            pair_fuse_k<<<(E_ * 100 + 255) / 256, 256, 0, stream>>>(
                uv, h_b1, src0, dst0, p1, -1, E_);
            mfma_gemm_k<1, true, true, false, false><<<dim3((OUT_ + 127) / 128, E_ / 128), 256, 0, stream>>>(
                nullptr, p1, hw2t, h_b2, p2, nullptr, E_, OUT_, PAIR_, zbuf,
                nullptr, nullptr, nullptr, 0);
            head3_k<<<(E_ + 15) / 16, 256, 0, stream>>>(p2, h_w3, h_b3, out,
                                                        b * E_, E_);
        }
    }
}

// Round 4
// 1646.728 us; speedup vs baseline: 1.3300x; 1.3300x over previous
//
#include <hip/hip_runtime.h>
#include <hip/hip_bf16.h>

typedef unsigned short u16;   // bf16 bits
typedef __attribute__((ext_vector_type(8))) short bf16x8;   // MFMA A/B frag
typedef __attribute__((ext_vector_type(4))) float f32x4;    // MFMA C/D frag

#define B_   32
#define N_   1024
#define E_   16384
#define ET_  17408            // E_ + N_ self-loops
#define IN_DIM 768
#define HID  512
#define OUT_ 400
#define PAIR_ 800
#define UVW_ 1600             // U(800) ++ V(800) per node
#define FEAT_ELEMS 13107200   // B_*N_*OUT_
#define MAXD 128

__device__ __forceinline__ float u2f(u16 u) {
    union { unsigned int i; float f; } v; v.i = ((unsigned int)u) << 16; return v.f;
}
__device__ __forceinline__ u16 f2u(float f) {
    __hip_bfloat16 h = __float2bfloat16(f);   // RNE, HW cvt on gfx950
    return *(u16*)&h;
}
__device__ __forceinline__ unsigned int pack2(float a, float b) {
    return (unsigned int)f2u(a) | ((unsigned int)f2u(b) << 16);
}

__device__ __forceinline__ float gelu_f(float x) {
    const float c = 0.7978845608028654f;          // sqrt(2/pi)
    float u = c * (x + 0.044715f * x * x * x);
    float t = 2.0f / (1.0f + __expf(-2.0f * u)) - 1.0f;   // tanh(u), overflow-safe
    return 0.5f * x * (1.0f + t);
}

// async global->LDS, 16 B per lane; LDS dest is wave-uniform base + lane*16
__device__ __forceinline__ void load_lds16(const void* g, void* l) {
    __builtin_amdgcn_global_load_lds(
        (const __attribute__((address_space(1))) void*)g,
        (__attribute__((address_space(3))) void*)l, 16, 0, 0);
}

// ---------------------------------------------------------------------------
// Weight transpose + bf16 convert: Wt[n][k] = bf16(W[k][n]). Tiny, once/launch.
// ---------------------------------------------------------------------------
__global__ void wt_k(const float* __restrict__ W, u16* __restrict__ Wt,
                     int K, int N)
{
    int i = blockIdx.x * 256 + threadIdx.x;
    if (i >= N * K) return;
    int n = i / K, k = i - n * K;
    Wt[i] = f2u(W[(size_t)k * N + n]);
}

// h_w1 [800][800] -> uvwt [1600][400] bf16 (transposed, halves split):
//   n <  800: uvwt[n][k]   = h_w1[k][n]          (U = feat @ h_w1[0:400,:])
//   n >= 800: uvwt[n][k]   = h_w1[400+k][n-800]  (V = feat @ h_w1[400:800,:])
__global__ void wtuv_k(const float* __restrict__ W, u16* __restrict__ Wt)
{
    int i = blockIdx.x * 256 + threadIdx.x;       // over 1600*400
    if (i >= UVW_ * OUT_) return;
    int n = i / OUT_, k = i - n * OUT_;
    int row = (n >= PAIR_) ? OUT_ + k : k;
    int col = (n >= PAIR_) ? n - PAIR_ : n;
    Wt[i] = f2u(W[(size_t)row * PAIR_ + col]);
}

// f32 -> bf16 bulk convert, 8 elems/lane
__global__ void f2b_k(const float* __restrict__ X, u16* __restrict__ Y, int n8)
{
    int i = blockIdx.x * 256 + threadIdx.x;
    if (i >= n8) return;
    const float4* p = (const float4*)X + (size_t)i * 2;
    float4 a = p[0], b = p[1];
    uint4 o;
    o.x = pack2(a.x, a.y); o.y = pack2(a.z, a.w);
    o.z = pack2(b.x, b.y); o.w = pack2(b.z, b.w);
    ((uint4*)Y)[i] = o;
}

// ---------------------------------------------------------------------------
// MFMA GEMM: C[M,N] = act(A[M,K] @ W[K,N] + bias), f32 accumulate.
// Tile 128x128, BK=64; 4 waves, each 64x64 via 4x4 grid of 16x16x32 MFMAs.
// Wt pre-transposed bf16 [N][K].
// ASRC: 0 = f32 A (VGPR cvt staging); 1 = bf16 A (async global_load_lds).
// T1 XCD-chunked bijective swizzle (m204): co-locate a row-tile's col-tiles
// on one XCD so the A panel is fetched into that XCD's L2 once.
// FUSE_H3: no C store. Contract in-register tile with w3 [N][3] after
// gelu(.+bias): shfl-reduce over lm, LDS-combine the 2 wn waves, then
// NON-ATOMIC partial store part[bnIdx][row][3] (4 col-tile slices).
// red3_k sums the 4 slices + b3 afterwards. (Atomics in r3 caused 48MB
// write-through + serialization: 194us/chunk. This is the fix.)
// LDS layout: unpadded pitch 128 B, XOR swizzle phys_chunk = log_chunk^(row&7)
// (16B chunks) -> global_load_lds lane-contiguity satisfied AND quarter-wave
// ds_read_b128 is uniform 2-way on banks (free, m136). OOB lanes read zbuf.
// ---------------------------------------------------------------------------
template<int ASRC, bool DO_GELU, bool HAS_BIAS, bool OUT_F32, bool FUSE_H3>
__global__ __launch_bounds__(256)
void mfma_gemm_k(const float* __restrict__ Af, const u16* __restrict__ Ab,
                 const u16* __restrict__ Wt, const float* __restrict__ bias,
                 u16* __restrict__ Cb, float* __restrict__ Cf,
                 int M, int N, int K,
                 const u16* __restrict__ zbuf,
                 const float* __restrict__ w3p, float* __restrict__ partp)
{
    __shared__ __align__(16) u16 As[128 * 64];
    __shared__ __align__(16) u16 Bs[128 * 64];
    const int tid  = threadIdx.x;
    // --- T1 bijective XCD swizzle ---
    const int gx   = gridDim.x;
    const int nwg  = gx * gridDim.y;
    const int orig = blockIdx.y * gx + blockIdx.x;
    const int qc   = nwg >> 3, rc = nwg & 7;
    const int xcd  = orig & 7, lid = orig >> 3;
    const int wg   = ((xcd < rc) ? xcd * (qc + 1) : rc * (qc + 1) + (xcd - rc) * qc) + lid;
    const int bnIdx= wg % gx;
    const int bm   = (wg / gx) * 128;
    const int bn   = bnIdx * 128;
    const int wave = tid >> 6;
    const int lane = tid & 63;
    const int wm   = (wave >> 1) * 64;
    const int wn   = (wave & 1) * 64;
    const int lm   = lane & 15;
    const int lq   = lane >> 4;
    const int lb   = lm & 7;
    // async-staging lane geometry: instr c4 covers rows w*32+c4*8 .. +7
    const int l8 = lane >> 3;            // row within 8-row group
    const int cl = (lane & 7) ^ l8;      // logical 8-elem chunk for this lane

    // per-c4 row metadata
    size_t arow[4]; size_t brow[4]; bool bok[4];
    #pragma unroll
    for (int c4 = 0; c4 < 4; ++c4) {
        int rt = wave * 32 + c4 * 8 + l8;          // tile row 0..127
        if (ASRC == 1) arow[c4] = (size_t)(bm + rt) * K;
        int n = bn + rt;
        bok[c4] = (n < N);
        brow[c4] = (size_t)(n < N ? n : 0) * K;
    }
    // VGPR-staging geometry (ASRC 0)
    const int vrow = tid >> 1, vhalf = tid & 1;

    f32x4 acc[4][4] = {};

    for (int k0 = 0; k0 < K; k0 += 64) {
        // ---- stage A
        if (ASRC == 1) {
            int kk = k0 + cl * 8;
            #pragma unroll
            for (int c4 = 0; c4 < 4; ++c4) {
                const u16* ga = (kk < K) ? Ab + arow[c4] + kk : zbuf;
                load_lds16(ga, (char*)As + (wave * 32 + c4 * 8) * 128);
            }
        } else {
            #pragma unroll
            for (int c = 0; c < 4; ++c) {
                int c_log = vhalf * 4 + c;
                int kk = k0 + c_log * 8;
                uint4 wv = make_uint4(0, 0, 0, 0);
                if (kk < K) {
                    const float* p = Af + (size_t)(bm + vrow) * K + kk;
                    float4 v0 = *(const float4*)p;
                    float4 v1 = *(const float4*)(p + 4);
                    wv.x = pack2(v0.x, v0.y); wv.y = pack2(v0.z, v0.w);
                    wv.z = pack2(v1.x, v1.y); wv.w = pack2(v1.z, v1.w);
                }
                int pc = c_log ^ (vrow & 7);
                *(uint4*)((char*)As + vrow * 128 + pc * 16) = wv;
            }
        }
        // ---- stage B (always async; Wt bf16 [N][K])
        {
            int kk = k0 + cl * 8;
            #pragma unroll
            for (int c4 = 0; c4 < 4; ++c4) {
                const u16* gb = (bok[c4] && kk < K) ? Wt + brow[c4] + kk : zbuf;
                load_lds16(gb, (char*)Bs + (wave * 32 + c4 * 8) * 128);
            }
        }
        __syncthreads();
        #pragma unroll
        for (int kh = 0; kh < 2; ++kh) {
            bf16x8 af[4], bfr[4];
            #pragma unroll
            for (int t = 0; t < 4; ++t)
                af[t] = *(const bf16x8*)((const char*)As +
                        (wm + t * 16 + lm) * 128 + (((kh * 4 + lq) ^ lb) * 16));
            #pragma unroll
            for (int u = 0; u < 4; ++u)
                bfr[u] = *(const bf16x8*)((const char*)Bs +
                        (wn + u * 16 + lm) * 128 + (((kh * 4 + lq) ^ lb) * 16));
            #pragma unroll
            for (int t = 0; t < 4; ++t)
                #pragma unroll
                for (int u = 0; u < 4; ++u)
                    acc[t][u] = __builtin_amdgcn_mfma_f32_16x16x32_bf16(
                        af[t], bfr[u], acc[t][u], 0, 0, 0);
        }
        __syncthreads();
    }

    // ---- fused head3 epilogue: part[bnIdx][row] += gelu(p2_tile) @ w3
    if (FUSE_H3) {
        float w3c[4][3]; float bvv[4];
        #pragma unroll
        for (int u = 0; u < 4; ++u) {
            int col = bn + wn + u * 16 + lm;
            bool ok = (col < N);
            bvv[u]    = ok ? bias[col] : 0.f;
            w3c[u][0] = ok ? w3p[col * 3 + 0] : 0.f;
            w3c[u][1] = ok ? w3p[col * 3 + 1] : 0.f;
            w3c[u][2] = ok ? w3p[col * 3 + 2] : 0.f;
        }
        float* red = (float*)As;         // [4 waves][64 rows][3], 3 KB, As dead
        #pragma unroll
        for (int t = 0; t < 4; ++t) {
            #pragma unroll
            for (int r = 0; r < 4; ++r) {
                float s0 = 0.f, s1 = 0.f, s2 = 0.f;
                #pragma unroll
                for (int u = 0; u < 4; ++u) {
                    float v = gelu_f(acc[t][u][r] + bvv[u]);
                    s0 += v * w3c[u][0];
                    s1 += v * w3c[u][1];
                    s2 += v * w3c[u][2];
                }
                #pragma unroll
                for (int off = 8; off; off >>= 1) {
                    s0 += __shfl_xor(s0, off);
                    s1 += __shfl_xor(s1, off);
                    s2 += __shfl_xor(s2, off);
                }
                if (lm == 0) {
                    int lr = t * 16 + lq * 4 + r;            // 0..63 within wave
                    float* d = red + (wave * 64 + lr) * 3;
                    d[0] = s0; d[1] = s1; d[2] = s2;
                }
            }
        }
        __syncthreads();
        if ((wave & 1) == 0 && lane < 64) {       // waves 0,2 combine wn pair
            int lr = lane;
            int rowg = bm + wm + lr;
            float* a = red + ((wave + 0) * 64 + lr) * 3;
            float* b = red + ((wave + 1) * 64 + lr) * 3;
            float* d = partp + ((size_t)bnIdx * M + rowg) * 3;
            d[0] = a[0] + b[0];
            d[1] = a[1] + b[1];
            d[2] = a[2] + b[2];
        }
        return;
    }

    // ---- epilogue: C col = lane&15, row = quad*4 + reg (verified m89/m91)
    #pragma unroll
    for (int u = 0; u < 4; ++u) {
        int col = bn + wn + u * 16 + lm;
        if (col >= N) continue;
        float bv = HAS_BIAS ? bias[col] : 0.f;
        #pragma unroll
        for (int t = 0; t < 4; ++t) {
            #pragma unroll
            for (int r = 0; r < 4; ++r) {
                int rowg = bm + wm + t * 16 + lq * 4 + r;
                float v = acc[t][u][r] + bv;
                if (DO_GELU) v = gelu_f(v);
                if (OUT_F32) {
                    Cf[(size_t)rowg * N + col] = v;
                    if (Cb) Cb[(size_t)rowg * N + col] = f2u(v);  // dual write
                } else {
                    Cb[(size_t)rowg * N + col] = f2u(v);
                }
            }
        }
    }
}

// ---------------------------------------------------------------------------
// Partial reduce: pred[row_base+r,:] = b3 + sum_{s<4} part[s][r][:]
// ---------------------------------------------------------------------------
__global__ __launch_bounds__(256)
void red3_k(const float* __restrict__ part, const float* __restrict__ b3,
            float* __restrict__ out, int row_base, int Mr)
{
    int r = blockIdx.x * 256 + threadIdx.x;
    if (r >= Mr) return;
    float s0 = b3[0], s1 = b3[1], s2 = b3[2];
    #pragma unroll
    for (int s = 0; s < 4; ++s) {
        const float* p = part + ((size_t)s * Mr + r) * 3;
        s0 += p[0]; s1 += p[1]; s2 += p[2];
    }
    float* d = out + (size_t)FEAT_ELEMS + (size_t)(row_base + r) * 3;
    d[0] = s0; d[1] = s1; d[2] = s2;
}

// ---------------------------------------------------------------------------
// Pair fuse: p1[r,:] = gelu(U[src] + V[dst] + b1)  (distributed head GEMM1).
// UV bf16 [nodes][1600] = [U(800) | V(800)]. Flattened: 1 thread = one 8-elem
// chunk (row = idx/100 via magic div); no idle lanes. UV rows L3-resident.
// ---------------------------------------------------------------------------
__global__ __launch_bounds__(256)
void pair_fuse_k(const u16* __restrict__ UV, const float* __restrict__ b1,
                 const int* __restrict__ src0, const int* __restrict__ dst0,
                 u16* __restrict__ p1, int b0, int nrows)
{
    unsigned idx = blockIdx.x * 256u + threadIdx.x;
    unsigned total = (unsigned)nrows * 100u;
    if (idx >= total) return;
    unsigned r  = (unsigned)(((unsigned long long)idx * 1374389535ull) >> 37); // /100
    unsigned c8 = idx - r * 100u;
    int e = r & (E_ - 1);
    int gs, gd;
    if (b0 >= 0) {                        // big mode: global node ids
        int b = b0 + (int)(r >> 14);
        gs = (b << 10) + src0[e];
        gd = (b << 10) + dst0[e];
    } else {                              // small mode: per-batch UV table
        gs = src0[e]; gd = dst0[e];
    }
    uint4 qu = *(const uint4*)(UV + (size_t)gs * UVW_ + c8 * 8);
    uint4 qv = *(const uint4*)(UV + (size_t)gd * UVW_ + PAIR_ + c8 * 8);
    float4 bva = *(const float4*)(b1 + c8 * 8);
    float4 bvb = *(const float4*)(b1 + c8 * 8 + 4);
    float bb[8] = {bva.x, bva.y, bva.z, bva.w, bvb.x, bvb.y, bvb.z, bvb.w};
    unsigned int uu[4] = {qu.x, qu.y, qu.z, qu.w};
    unsigned int vv[4] = {qv.x, qv.y, qv.z, qv.w};
    uint4 o; unsigned int* op = (unsigned int*)&o;
    #pragma unroll
    for (int q = 0; q < 4; ++q) {
        float a0 = u2f((u16)(uu[q] & 0xffff)) + u2f((u16)(vv[q] & 0xffff)) + bb[2*q];
        float a1 = u2f((u16)(uu[q] >> 16))    + u2f((u16)(vv[q] >> 16))    + bb[2*q+1];
        op[q] = pack2(gelu_f(a0), gelu_f(a1));
    }
    *(uint4*)(p1 + (size_t)r * PAIR_ + c8 * 8) = o;
}

// ---------------------------------------------------------------------------
// Attention scores: a_s[n,h] = sum_f wh[n,h*200+f]*att_src[h*200+f]; same a_d.
// ---------------------------------------------------------------------------
__global__ __launch_bounds__(256)
void scores_k(const u16* __restrict__ wh, const float* __restrict__ att_s,
              const float* __restrict__ att_d, float* __restrict__ a_s,
              float* __restrict__ a_d)
{
    int n = blockIdx.x * 4 + (threadIdx.x >> 6);
    int lane = threadIdx.x & 63;
    const u16* row = wh + (size_t)n * OUT_;
    float as0 = 0, as1 = 0, ad0 = 0, ad1 = 0;
    for (int f = lane; f < OUT_; f += 64) {
        float v = u2f(row[f]);
        float s = att_s[f];
        float d = att_d[f];
        if (f < 200) { as0 += v * s; ad0 += v * d; }
        else         { as1 += v * s; ad1 += v * d; }
    }
    for (int off = 32; off; off >>= 1) {
        as0 += __shfl_xor(as0, off); as1 += __shfl_xor(as1, off);
        ad0 += __shfl_xor(ad0, off); ad1 += __shfl_xor(ad1, off);
    }
    if (lane == 0) {
        a_s[(size_t)n * 2 + 0] = as0; a_s[(size_t)n * 2 + 1] = as1;
        a_d[(size_t)n * 2 + 0] = ad0; a_d[(size_t)n * 2 + 1] = ad1;
    }
}

// ---------------------------------------------------------------------------
// CSR build (edges shared across batches; incl. self-loops)
// ---------------------------------------------------------------------------
__global__ void csr_count_k(const int* __restrict__ edges, int* __restrict__ deg)
{
    int et = blockIdx.x * blockDim.x + threadIdx.x;
    if (et >= ET_) return;
    int dst = (et < E_) ? edges[E_ + et] : (et - E_);
    atomicAdd(&deg[dst], 1);
}

__global__ __launch_bounds__(1024)
void csr_scan_k(const int* __restrict__ deg, int* __restrict__ row_ptr,
                int* __restrict__ cnt)
{
    __shared__ int s[1024];
    int t = threadIdx.x;
    int d = deg[t];
    s[t] = d;
    __syncthreads();
    for (int off = 1; off < 1024; off <<= 1) {
        int v = (t >= off) ? s[t - off] : 0;
        __syncthreads();
        s[t] += v;
        __syncthreads();
    }
    row_ptr[t] = s[t] - d;   // exclusive
    cnt[t] = s[t] - d;
    if (t == 1023) row_ptr[1024] = s[t];
}

__global__ void csr_fill_k(const int* __restrict__ edges, int* __restrict__ cnt,
                           int* __restrict__ col_src)
{
    int et = blockIdx.x * blockDim.x + threadIdx.x;
    if (et >= ET_) return;
    int src, dst;
    if (et < E_) { src = edges[et]; dst = edges[E_ + et]; }
    else         { src = et - E_;  dst = src; }
    int pos = atomicAdd(&cnt[dst], 1);
    col_src[pos] = src;
}

// ---------------------------------------------------------------------------
// Fused GAT softmax + aggregation + residual, in place on f32 feat (d_out).
// Vectorized: lane<50 handles 8 contiguous cols via uint4 wh loads; 4 j-slices
// (one per wave) reduced through padded LDS partials. Optionally emits bf16
// copy of feat (featb16) for the UV GEMM.
// ---------------------------------------------------------------------------
__global__ __launch_bounds__(256)
void gat_k(const u16* __restrict__ wh,
           const float* __restrict__ a_s, const float* __restrict__ a_d,
           const int* __restrict__ row_ptr, const int* __restrict__ col_src,
           const float* __restrict__ gat_b, float* __restrict__ feat,
           u16* __restrict__ featb16)
{
    int gn = blockIdx.x;                  // b*1024 + n
    int b = gn >> 10, n = gn & 1023;
    int tid = threadIdx.x;
    __shared__ float s_ee[2][MAXD];
    __shared__ int   s_src[MAXD];
    __shared__ float s_misc[6];           // m0,m1,invz0,invz1,ad0,ad1
    __shared__ float s_part[4][50][9];    // +1 pad col: spread banks
    int start = row_ptr[n];
    int deg = row_ptr[n + 1] - start;

    if (tid < 64) {
        int lane = tid;
        float ad0 = a_d[(size_t)gn * 2 + 0];
        float ad1 = a_d[(size_t)gn * 2 + 1];
        float m0 = -1e30f, m1 = -1e30f;
        for (int j = lane; j < deg; j += 64) {
            int gs = (b << 10) + col_src[start + j];
            float e0 = a_s[(size_t)gs * 2 + 0] + ad0; e0 = (e0 > 0.f) ? e0 : 0.2f * e0;
            float e1 = a_s[(size_t)gs * 2 + 1] + ad1; e1 = (e1 > 0.f) ? e1 : 0.2f * e1;
            if (j < MAXD) { s_ee[0][j] = e0; s_ee[1][j] = e1; s_src[j] = gs; }
            m0 = fmaxf(m0, e0); m1 = fmaxf(m1, e1);
        }
        for (int off = 32; off; off >>= 1) {
            m0 = fmaxf(m0, __shfl_xor(m0, off));
            m1 = fmaxf(m1, __shfl_xor(m1, off));
        }
        float z0 = 0.f, z1 = 0.f;
        for (int j = lane; j < deg; j += 64) {
            float e0, e1;
            if (j < MAXD) { e0 = s_ee[0][j]; e1 = s_ee[1][j]; }
            else {
                int gs = (b << 10) + col_src[start + j];
                e0 = a_s[(size_t)gs * 2 + 0] + ad0; e0 = (e0 > 0.f) ? e0 : 0.2f * e0;
                e1 = a_s[(size_t)gs * 2 + 1] + ad1; e1 = (e1 > 0.f) ? e1 : 0.2f * e1;
            }
            float t0 = __expf(e0 - m0), t1 = __expf(e1 - m1);
            if (j < MAXD) { s_ee[0][j] = t0; s_ee[1][j] = t1; }
            z0 += t0; z1 += t1;
        }
        for (int off = 32; off; off >>= 1) {
            z0 += __shfl_xor(z0, off);
            z1 += __shfl_xor(z1, off);
        }
        if (lane == 0) {
            s_misc[0] = m0; s_misc[1] = m1;
            s_misc[2] = (z0 > 0.f) ? 1.f / z0 : 0.f;
            s_misc[3] = (z1 > 0.f) ? 1.f / z1 : 0.f;
            s_misc[4] = ad0; s_misc[5] = ad1;
        }
    }
    __syncthreads();

    int wv = tid >> 6, ln = tid & 63;
    if (ln < 50) {
        int h = (ln >= 25);
        float m = s_misc[h], ad = s_misc[4 + h];
        float acc[8] = {};
        for (int j = wv; j < deg; j += 4) {
            float w; int gs;
            if (j < MAXD) { w = s_ee[h][j]; gs = s_src[j]; }
            else {
                gs = (b << 10) + col_src[start + j];
                float e = a_s[(size_t)gs * 2 + h] + ad;
                e = (e > 0.f) ? e : 0.2f * e;
                w = __expf(e - m);
            }
            uint4 q = *(const uint4*)(wh + (size_t)gs * OUT_ + ln * 8);
            acc[0] += w * u2f((u16)(q.x & 0xffff));
            acc[1] += w * u2f((u16)(q.x >> 16));
            acc[2] += w * u2f((u16)(q.y & 0xffff));
            acc[3] += w * u2f((u16)(q.y >> 16));
            acc[4] += w * u2f((u16)(q.z & 0xffff));
            acc[5] += w * u2f((u16)(q.z >> 16));
            acc[6] += w * u2f((u16)(q.w & 0xffff));
            acc[7] += w * u2f((u16)(q.w >> 16));
        }
        #pragma unroll
        for (int k = 0; k < 8; ++k) s_part[wv][ln][k] = acc[k];
    }
    __syncthreads();
    if (tid < 50) {
        int h = (tid >= 25);
        float iz = s_misc[2 + h];
        size_t base = (size_t)gn * OUT_ + tid * 8;
        float4 f0 = *(const float4*)(feat + base);
        float4 f1 = *(const float4*)(feat + base + 4);
        float fv[8] = { f0.x, f0.y, f0.z, f0.w, f1.x, f1.y, f1.z, f1.w };
        float o[8];
        #pragma unroll
        for (int k = 0; k < 8; ++k) {
            float s = s_part[0][tid][k] + s_part[1][tid][k] +
                      s_part[2][tid][k] + s_part[3][tid][k];
            o[k] = fv[k] + s * iz + gat_b[tid * 8 + k];
        }
        *(float4*)(feat + base)     = make_float4(o[0], o[1], o[2], o[3]);
        *(float4*)(feat + base + 4) = make_float4(o[4], o[5], o[6], o[7]);
        if (featb16) {
            uint4 bq;
            bq.x = pack2(o[0], o[1]); bq.y = pack2(o[2], o[3]);
            bq.z = pack2(o[4], o[5]); bq.w = pack2(o[6], o[7]);
            *(uint4*)(featb16 + base) = bq;
        }
    }
}

// ---------------------------------------------------------------------------
// Final tiny GEMM (small-mode only): pred[e,:] = p2[e,:] @ w3[400,3] + b3.
// ---------------------------------------------------------------------------
__global__ __launch_bounds__(256)
void head3_k(const u16* __restrict__ p2, const float* __restrict__ w3,
             const float* __restrict__ b3, float* __restrict__ out,
             int row_base, int nrows)
{
    int wv = threadIdx.x >> 6, lane = threadIdx.x & 63;
    float w3r[24];
    if (lane < 50) {
        #pragma unroll
        for (int q = 0; q < 6; ++q) {
            float4 v = *(const float4*)(w3 + lane * 24 + q * 4);
            w3r[q * 4 + 0] = v.x; w3r[q * 4 + 1] = v.y;
            w3r[q * 4 + 2] = v.z; w3r[q * 4 + 3] = v.w;
        }
    }
    int e0 = blockIdx.x * 16 + wv * 4;
    for (int ei = 0; ei < 4; ++ei) {
        int e = e0 + ei;
        if (e >= nrows) break;
        float s0 = 0, s1 = 0, s2 = 0;
        if (lane < 50) {
            uint4 q = *(const uint4*)(p2 + (size_t)e * OUT_ + lane * 8);
            float f[8];
            f[0] = u2f((u16)(q.x & 0xffff)); f[1] = u2f((u16)(q.x >> 16));
            f[2] = u2f((u16)(q.y & 0xffff)); f[3] = u2f((u16)(q.y >> 16));
            f[4] = u2f((u16)(q.z & 0xffff)); f[5] = u2f((u16)(q.z >> 16));
            f[6] = u2f((u16)(q.w & 0xffff)); f[7] = u2f((u16)(q.w >> 16));
            #pragma unroll
            for (int k = 0; k < 8; ++k) {
                s0 += f[k] * w3r[k * 3 + 0];
                s1 += f[k] * w3r[k * 3 + 1];
                s2 += f[k] * w3r[k * 3 + 2];
            }
        }
        for (int off = 32; off; off >>= 1) {
            s0 += __shfl_xor(s0, off);
            s1 += __shfl_xor(s1, off);
            s2 += __shfl_xor(s2, off);
        }
        if (lane == 0) {
            size_t o = (size_t)FEAT_ELEMS + (size_t)(row_base + e) * 3;
            out[o + 0] = s0 + b3[0];
            out[o + 1] = s1 + b3[1];
            out[o + 2] = s2 + b3[2];
        }
    }
}

extern "C" void kernel_launch(void* const* d_in, const int* in_sizes, int n_in,
                              void* d_out, int out_size, void* d_ws, size_t ws_size,
                              hipStream_t stream)
{
    const float* patch  = (const float*)d_in[0];
    const int*   edges  = (const int*)d_in[1];
    const float* enc_w1 = (const float*)d_in[2];
    const float* enc_b1 = (const float*)d_in[3];
    const float* enc_w2 = (const float*)d_in[4];
    const float* enc_b2 = (const float*)d_in[5];
    const float* gat_w  = (const float*)d_in[6];
    const float* att_s  = (const float*)d_in[7];
    const float* att_d  = (const float*)d_in[8];
    const float* gat_b  = (const float*)d_in[9];
    const float* h_w1   = (const float*)d_in[10];
    const float* h_b1   = (const float*)d_in[11];
    const float* h_w2   = (const float*)d_in[12];
    const float* h_b2   = (const float*)d_in[13];
    const float* h_w3   = (const float*)d_in[14];
    const float* h_b3   = (const float*)d_in[15];
    float* out  = (float*)d_out;
    float* feat = out;                          // f32 [32768,400] in d_out
    char*  ws   = (char*)d_ws;

    const int* src0 = edges;
    const int* dst0 = edges + E_;

    // --- mode select from ws_size (deterministic; graph-capture safe) ------
    // big-mode layout:
    //   [0,R0)                enc1 bf16 (33.5MB); featb16 overlays (dead enc1);
    //                         head-phase: part f32 [4][Mr][3] (3.1MB, CB=4)
    //   [R0, R0+26.2MB)       whb bf16            (dead after gat_k)
    //   [R0+26.2, R0+52.4MB)  encb16 bf16 (enc out, consumed by GAT linear)
    //   [R0, R0+UVSZ)         UV bf16 [32768,1600] (overlays whb+encb16, after)
    //   [R0+UVSZ, +CB*26.2MB) p1 chunk; patchb16 (50.3MB) overlays p1 early
    //   [ws_size-TAIL, ..)    weights + scores + CSR + zbuf
    // p2 eliminated (head3 fused into GEMM2 epilogue, non-atomic partials).
    // CB=4 keeps UV(105MB)+p1(105MB) L3-resident; CB>=2 needed for patchb16.
    const size_t R0 = 33554432ull, TAIL = 4194304ull;
    const size_t UVSZ = 104857600ull;           // 32768*1600*2
    const size_t P1SZ = 26214400ull;            // per-batch p1
    int CB = 0;
    if      (ws_size >= R0 + UVSZ + TAIL + 4 * P1SZ) CB = 4;
    else if (ws_size >= R0 + UVSZ + TAIL + 2 * P1SZ) CB = 2;
    const bool big = (CB >= 2);

    u16 *enc1, *whb, *p1, *p2, *featb16, *uv, *w1t, *w2t, *gwt, *uvwt, *hw2t;
    u16 *patchb16, *encb16;
    float *a_s, *a_d, *part; int *deg;
    if (big) {
        enc1    = (u16*)ws;
        featb16 = (u16*)ws;                     // overlays enc1 (dead)
        part    = (float*)ws;                   // head-phase reuse (featb16 dead)
        whb     = (u16*)(ws + R0);
        uv      = (u16*)(ws + R0);              // overlays whb (dead after gat)
        encb16  = (u16*)(ws + R0 + 26214400ull);// enc bf16, dead before UV GEMM
        p1      = (u16*)(ws + R0 + UVSZ);
        patchb16= (u16*)(ws + R0 + UVSZ);       // overlays p1 (dead before head)
        p2      = nullptr;
        size_t tb = (ws_size - TAIL) & ~(size_t)255;
        w1t  = (u16*)(ws + tb);
        w2t  = (u16*)(ws + tb + 786432);
        gwt  = (u16*)(ws + tb + 1196032);
        uvwt = (u16*)(ws + tb + 1516032);       // 1600*400*2 = 1,280,000
        hw2t = (u16*)(ws + tb + 2796032);
        a_s  = (float*)(ws + tb + 3436032);
        a_d  = (float*)(ws + tb + 3698176);
        deg  = (int*)(ws + tb + 3960320);
    } else {
        // small mode: per-batch loop; UV table is per-batch [1024,1600] bf16
        enc1    = (u16*)ws;                     // sequenced overlays
        whb     = (u16*)ws;
        p1      = (u16*)ws;
        featb16 = nullptr;
        patchb16= nullptr;
        encb16  = nullptr;
        part    = nullptr;
        p2      = (u16*)(ws + 26214400);
        uv      = (u16*)(ws + 39321600);        // 1024*1600*2 = 3,276,800
        w1t  = (u16*)(ws + 42598400);
        w2t  = (u16*)(ws + 43384832);
        gwt  = (u16*)(ws + 43794432);
        uvwt = (u16*)(ws + 44114432);
        hw2t = (u16*)(ws + 45394432);
        a_s  = (float*)(ws + 46034432);
        a_d  = (float*)(ws + 46296576);
        deg  = (int*)(ws + 46558720);
    }
    int* row_ptr = deg + 1024;
    int* cnt     = row_ptr + 1032;
    int* col_src = cnt + 1024;
    u16* zbuf = (u16*)(col_src + 17408);        // 256 B zero scratch (16B aligned)

    hipMemsetAsync(zbuf, 0, 256, stream);

    // weight transposes (bf16), tiny
    wt_k<<<(HID * IN_DIM + 255) / 256, 256, 0, stream>>>(enc_w1, w1t, IN_DIM, HID);
    wt_k<<<(OUT_ * HID + 255) / 256, 256, 0, stream>>>(enc_w2, w2t, HID, OUT_);
    wt_k<<<(OUT_ * OUT_ + 255) / 256, 256, 0, stream>>>(gat_w, gwt, OUT_, OUT_);
    wtuv_k<<<(UVW_ * OUT_ + 255) / 256, 256, 0, stream>>>(h_w1, uvwt);
    wt_k<<<(OUT_ * PAIR_ + 255) / 256, 256, 0, stream>>>(h_w2, hw2t, PAIR_, OUT_);

    // CSR by dst (batch-independent)
    hipMemsetAsync(deg, 0, 1024 * sizeof(int), stream);
    csr_count_k<<<(ET_ + 255) / 256, 256, 0, stream>>>(edges, deg);
    csr_scan_k<<<1, 1024, 0, stream>>>(deg, row_ptr, cnt);
    csr_fill_k<<<(ET_ + 255) / 256, 256, 0, stream>>>(edges, cnt, col_src);

    if (big) {
        // patch -> bf16 once (numerics identical: staging already cvt'd)
        f2b_k<<<(B_ * N_ * IN_DIM / 8 + 255) / 256, 256, 0, stream>>>(
            patch, patchb16, B_ * N_ * IN_DIM / 8);
        // encoder: enc1 = gelu(patch @ w1 + b1)
        mfma_gemm_k<1, true, true, false, false><<<dim3(HID / 128, (B_ * N_) / 128), 256, 0, stream>>>(
            nullptr, patchb16, w1t, enc_b1, enc1, nullptr, B_ * N_, HID, IN_DIM, zbuf,
            nullptr, nullptr);
        // feat(f32, d_out) + encb16(bf16) = enc1 @ w2 + b2
        mfma_gemm_k<1, false, true, true, false><<<dim3((OUT_ + 127) / 128, (B_ * N_) / 128), 256, 0, stream>>>(
            nullptr, enc1, w2t, enc_b2, encb16, feat, B_ * N_, OUT_, HID, zbuf,
            nullptr, nullptr);
        // GAT linear: wh = enc(bf16) @ gat_w
        mfma_gemm_k<1, false, false, false, false><<<dim3((OUT_ + 127) / 128, (B_ * N_) / 128), 256, 0, stream>>>(
            nullptr, encb16, gwt, nullptr, whb, nullptr, B_ * N_, OUT_, OUT_, zbuf,
            nullptr, nullptr);
    } else {
        mfma_gemm_k<0, true, true, false, false><<<dim3(HID / 128, (B_ * N_) / 128), 256, 0, stream>>>(
            patch, nullptr, w1t, enc_b1, enc1, nullptr, B_ * N_, HID, IN_DIM, zbuf,
            nullptr, nullptr);
        mfma_gemm_k<1, false, true, true, false><<<dim3((OUT_ + 127) / 128, (B_ * N_) / 128), 256, 0, stream>>>(
            nullptr, enc1, w2t, enc_b2, nullptr, feat, B_ * N_, OUT_, HID, zbuf,
            nullptr, nullptr);
        mfma_gemm_k<0, false, false, false, false><<<dim3((OUT_ + 127) / 128, (B_ * N_) / 128), 256, 0, stream>>>(
            feat, nullptr, gwt, nullptr, whb, nullptr, B_ * N_, OUT_, OUT_, zbuf,
            nullptr, nullptr);
    }

    scores_k<<<(B_ * N_) / 4, 256, 0, stream>>>(whb, att_s, att_d, a_s, a_d);
    gat_k<<<B_ * N_, 256, 0, stream>>>(whb, a_s, a_d, row_ptr, col_src,
                                       gat_b, feat, featb16);

    // predict head — head GEMM1 distributed over the pair-gather:
    //   pair @ h_w1 = feat[src] @ h_w1[0:400,:] + feat[dst] @ h_w1[400:800,:]
    //              = U[src] + V[dst]   (per-NODE GEMM: 32x less FLOP)
    // GEMM2's epilogue contracts p2 (in registers) with w3 -> 4 non-atomic
    // partial slices; red3_k reduces them into pred.
    if (big) {
        // UV = featb16 @ uvwt  -> bf16 [32768,1600]
        mfma_gemm_k<1, false, false, false, false><<<dim3((UVW_ + 127) / 128, (B_ * N_) / 128), 256, 0, stream>>>(
            nullptr, featb16, uvwt, nullptr, uv, nullptr, B_ * N_, UVW_, OUT_, zbuf,
            nullptr, nullptr);
        for (int b0 = 0; b0 < B_; b0 += CB) {
            int Mr = CB * E_;
            pair_fuse_k<<<(Mr * 100 + 255) / 256, 256, 0, stream>>>(
                uv, h_b1, src0, dst0, p1, b0, Mr);
            mfma_gemm_k<1, true, true, false, true><<<dim3((OUT_ + 127) / 128, Mr / 128), 256, 0, stream>>>(
                nullptr, p1, hw2t, h_b2, nullptr, nullptr, Mr, OUT_, PAIR_, zbuf,
                h_w3, part);
            red3_k<<<(Mr + 255) / 256, 256, 0, stream>>>(part, h_b3, out, b0 * E_, Mr);
        }
    } else {
        for (int b = 0; b < B_; ++b) {
            const float* featb = feat + (size_t)b * N_ * OUT_;
            mfma_gemm_k<0, false, false, false, false><<<dim3((UVW_ + 127) / 128, N_ / 128), 256, 0, stream>>>(
                featb, nullptr, uvwt, nullptr, uv, nullptr, N_, UVW_, OUT_, zbuf,
                nullptr, nullptr);
            pair_fuse_k<<<(E_ * 100 + 255) / 256, 256, 0, stream>>>(
                uv, h_b1, src0, dst0, p1, -1, E_);
            mfma_gemm_k<1, true, true, false, false><<<dim3((OUT_ + 127) / 128, E_ / 128), 256, 0, stream>>>(
                nullptr, p1, hw2t, h_b2, p2, nullptr, E_, OUT_, PAIR_, zbuf,
                nullptr, nullptr);
            head3_k<<<(E_ + 15) / 16, 256, 0, stream>>>(p2, h_w3, h_b3, out,
                                                        b * E_, E_);
        }
    }
}

// Round 5
// 1631.358 us; speedup vs baseline: 1.3426x; 1.0094x over previous
//
#include <hip/hip_runtime.h>
#include <hip/hip_bf16.h>

typedef unsigned short u16;   // bf16 bits
typedef __attribute__((ext_vector_type(8))) short bf16x8;   // MFMA A/B frag
typedef __attribute__((ext_vector_type(4))) float f32x4;    // MFMA C/D frag

#define B_   32
#define N_   1024
#define E_   16384
#define ET_  17408            // E_ + N_ self-loops
#define IN_DIM 768
#define HID  512
#define OUT_ 400
#define PAIR_ 800
#define UVW_ 1600             // U(800) ++ V(800) per node
#define FEAT_ELEMS 13107200   // B_*N_*OUT_
#define MAXD 128

__device__ __forceinline__ float u2f(u16 u) {
    union { unsigned int i; float f; } v; v.i = ((unsigned int)u) << 16; return v.f;
}
__device__ __forceinline__ u16 f2u(float f) {
    __hip_bfloat16 h = __float2bfloat16(f);   // RNE, HW cvt on gfx950
    return *(u16*)&h;
}
__device__ __forceinline__ unsigned int pack2(float a, float b) {
    return (unsigned int)f2u(a) | ((unsigned int)f2u(b) << 16);
}

__device__ __forceinline__ float gelu_f(float x) {
    const float c = 0.7978845608028654f;          // sqrt(2/pi)
    float u = c * (x + 0.044715f * x * x * x);
    float t = 2.0f / (1.0f + __expf(-2.0f * u)) - 1.0f;   // tanh(u), overflow-safe
    return 0.5f * x * (1.0f + t);
}

// async global->LDS, 16 B per lane; LDS dest is wave-uniform base + lane*16
__device__ __forceinline__ void load_lds16(const void* g, void* l) {
    __builtin_amdgcn_global_load_lds(
        (const __attribute__((address_space(1))) void*)g,
        (__attribute__((address_space(3))) void*)l, 16, 0, 0);
}

// ---------------------------------------------------------------------------
// Weight transpose + bf16 convert: Wt[n][k] = bf16(W[k][n]). Tiny, once/launch.
// ---------------------------------------------------------------------------
__global__ void wt_k(const float* __restrict__ W, u16* __restrict__ Wt,
                     int K, int N)
{
    int i = blockIdx.x * 256 + threadIdx.x;
    if (i >= N * K) return;
    int n = i / K, k = i - n * K;
    Wt[i] = f2u(W[(size_t)k * N + n]);
}

// h_w1 [800][800] -> uvwt [1600][400] bf16 (transposed, halves split):
//   n <  800: uvwt[n][k]   = h_w1[k][n]          (U = feat @ h_w1[0:400,:])
//   n >= 800: uvwt[n][k]   = h_w1[400+k][n-800]  (V = feat @ h_w1[400:800,:])
__global__ void wtuv_k(const float* __restrict__ W, u16* __restrict__ Wt)
{
    int i = blockIdx.x * 256 + threadIdx.x;       // over 1600*400
    if (i >= UVW_ * OUT_) return;
    int n = i / OUT_, k = i - n * OUT_;
    int row = (n >= PAIR_) ? OUT_ + k : k;
    int col = (n >= PAIR_) ? n - PAIR_ : n;
    Wt[i] = f2u(W[(size_t)row * PAIR_ + col]);
}

// f32 -> bf16 bulk convert, 8 elems/lane
__global__ void f2b_k(const float* __restrict__ X, u16* __restrict__ Y, int n8)
{
    int i = blockIdx.x * 256 + threadIdx.x;
    if (i >= n8) return;
    const float4* p = (const float4*)X + (size_t)i * 2;
    float4 a = p[0], b = p[1];
    uint4 o;
    o.x = pack2(a.x, a.y); o.y = pack2(a.z, a.w);
    o.z = pack2(b.x, b.y); o.w = pack2(b.z, b.w);
    ((uint4*)Y)[i] = o;
}

// ---------------------------------------------------------------------------
// MFMA GEMM: C[M,N] = act(A[M,K] @ W[K,N] + bias), f32 accumulate.
// Tile 128x128, BK=64; 4 waves, each 64x64 via 4x4 grid of 16x16x32 MFMAs.
// Wt pre-transposed bf16 [N][K].
// ASRC: 0 = f32 A (VGPR cvt staging, single-buffer); 1 = bf16 A (async
//       global_load_lds, DOUBLE-BUFFERED + counted vmcnt).
// 2-phase pipeline (T3 minimum recipe): issue next tile's 8 global_load_lds
// per wave BEFORE computing current tile; s_waitcnt vmcnt(8) (not 0!) + raw
// s_barrier -> next-tile loads stay in flight under the MFMA work. This
// attacks the r4 latency-bound profile (MfmaUtil 19%, VALU 53%, HBM 6%).
// T1 XCD-chunked bijective swizzle (m204): co-locate a row-tile's col-tiles
// on one XCD so the A panel is fetched into that XCD's L2 once.
// FUSE_H3: no C store. Contract in-register tile with w3 [N][3] after
// gelu(.+bias): shfl-reduce over lm, LDS-combine the 2 wn waves, then
// NON-ATOMIC partial store part[bnIdx][row][3]; red3_k reduces 4 slices.
// LDS layout: unpadded pitch 128 B, XOR swizzle phys_chunk = log_chunk^(row&7)
// (16B chunks) -> global_load_lds lane-contiguity satisfied AND quarter-wave
// ds_read_b128 is uniform 2-way on banks (free, m136). OOB lanes read zbuf.
// ---------------------------------------------------------------------------
template<int ASRC, bool DO_GELU, bool HAS_BIAS, bool OUT_F32, bool FUSE_H3>
__global__ __launch_bounds__(256)
void mfma_gemm_k(const float* __restrict__ Af, const u16* __restrict__ Ab,
                 const u16* __restrict__ Wt, const float* __restrict__ bias,
                 u16* __restrict__ Cb, float* __restrict__ Cf,
                 int M, int N, int K,
                 const u16* __restrict__ zbuf,
                 const float* __restrict__ w3p, float* __restrict__ partp)
{
    __shared__ __align__(16) u16 As[2][128 * 64];
    __shared__ __align__(16) u16 Bs[2][128 * 64];
    const int tid  = threadIdx.x;
    // --- T1 bijective XCD swizzle ---
    const int gx   = gridDim.x;
    const int nwg  = gx * gridDim.y;
    const int orig = blockIdx.y * gx + blockIdx.x;
    const int qc   = nwg >> 3, rc = nwg & 7;
    const int xcd  = orig & 7, lid = orig >> 3;
    const int wg   = ((xcd < rc) ? xcd * (qc + 1) : rc * (qc + 1) + (xcd - rc) * qc) + lid;
    const int bnIdx= wg % gx;
    const int bm   = (wg / gx) * 128;
    const int bn   = bnIdx * 128;
    const int wave = tid >> 6;
    const int lane = tid & 63;
    const int wm   = (wave >> 1) * 64;
    const int wn   = (wave & 1) * 64;
    const int lm   = lane & 15;
    const int lq   = lane >> 4;
    const int lb   = lm & 7;
    // async-staging lane geometry: instr c4 covers rows w*32+c4*8 .. +7
    const int l8 = lane >> 3;            // row within 8-row group
    const int cl = (lane & 7) ^ l8;      // logical 8-elem chunk for this lane

    // per-c4 row metadata
    size_t arow[4]; size_t brow[4]; bool bok[4];
    #pragma unroll
    for (int c4 = 0; c4 < 4; ++c4) {
        int rt = wave * 32 + c4 * 8 + l8;          // tile row 0..127
        if (ASRC == 1) arow[c4] = (size_t)(bm + rt) * K;
        int n = bn + rt;
        bok[c4] = (n < N);
        brow[c4] = (size_t)(n < N ? n : 0) * K;
    }
    // VGPR-staging geometry (ASRC 0)
    const int vrow = tid >> 1, vhalf = tid & 1;

    f32x4 acc[4][4] = {};
    const int NT = (K + 63) >> 6;

    if (ASRC == 1) {
        auto stage = [&](int buf, int k0) {
            int kk = k0 + cl * 8;
            #pragma unroll
            for (int c4 = 0; c4 < 4; ++c4) {
                const u16* ga = (kk < K) ? Ab + arow[c4] + kk : zbuf;
                load_lds16(ga, (char*)As[buf] + (wave * 32 + c4 * 8) * 128);
            }
            #pragma unroll
            for (int c4 = 0; c4 < 4; ++c4) {
                const u16* gb = (bok[c4] && kk < K) ? Wt + brow[c4] + kk : zbuf;
                load_lds16(gb, (char*)Bs[buf] + (wave * 32 + c4 * 8) * 128);
            }
        };
        stage(0, 0);
        int cur = 0;
        for (int it = 0; it < NT; ++it) {
            const bool last = (it == NT - 1);
            if (!last) stage(cur ^ 1, (it + 1) * 64);
            if (!last) asm volatile("s_waitcnt vmcnt(8)" ::: "memory");
            else       asm volatile("s_waitcnt vmcnt(0)" ::: "memory");
            __builtin_amdgcn_s_barrier();
            const char* Abase = (const char*)As[cur];
            const char* Bbase = (const char*)Bs[cur];
            #pragma unroll
            for (int kh = 0; kh < 2; ++kh) {
                bf16x8 af[4], bfr[4];
                #pragma unroll
                for (int t = 0; t < 4; ++t)
                    af[t] = *(const bf16x8*)(Abase +
                            (wm + t * 16 + lm) * 128 + (((kh * 4 + lq) ^ lb) * 16));
                #pragma unroll
                for (int u = 0; u < 4; ++u)
                    bfr[u] = *(const bf16x8*)(Bbase +
                            (wn + u * 16 + lm) * 128 + (((kh * 4 + lq) ^ lb) * 16));
                #pragma unroll
                for (int t = 0; t < 4; ++t)
                    #pragma unroll
                    for (int u = 0; u < 4; ++u)
                        acc[t][u] = __builtin_amdgcn_mfma_f32_16x16x32_bf16(
                            af[t], bfr[u], acc[t][u], 0, 0, 0);
            }
            asm volatile("" ::: "memory");
            __builtin_amdgcn_s_barrier();
            cur ^= 1;
        }
    } else {
        for (int k0 = 0; k0 < K; k0 += 64) {
            // ---- stage A (VGPR cvt)
            #pragma unroll
            for (int c = 0; c < 4; ++c) {
                int c_log = vhalf * 4 + c;
                int kk = k0 + c_log * 8;
                uint4 wv = make_uint4(0, 0, 0, 0);
                if (kk < K) {
                    const float* p = Af + (size_t)(bm + vrow) * K + kk;
                    float4 v0 = *(const float4*)p;
                    float4 v1 = *(const float4*)(p + 4);
                    wv.x = pack2(v0.x, v0.y); wv.y = pack2(v0.z, v0.w);
                    wv.z = pack2(v1.x, v1.y); wv.w = pack2(v1.z, v1.w);
                }
                int pc = c_log ^ (vrow & 7);
                *(uint4*)((char*)As[0] + vrow * 128 + pc * 16) = wv;
            }
            // ---- stage B (async)
            {
                int kk = k0 + cl * 8;
                #pragma unroll
                for (int c4 = 0; c4 < 4; ++c4) {
                    const u16* gb = (bok[c4] && kk < K) ? Wt + brow[c4] + kk : zbuf;
                    load_lds16(gb, (char*)Bs[0] + (wave * 32 + c4 * 8) * 128);
                }
            }
            __syncthreads();
            #pragma unroll
            for (int kh = 0; kh < 2; ++kh) {
                bf16x8 af[4], bfr[4];
                #pragma unroll
                for (int t = 0; t < 4; ++t)
                    af[t] = *(const bf16x8*)((const char*)As[0] +
                            (wm + t * 16 + lm) * 128 + (((kh * 4 + lq) ^ lb) * 16));
                #pragma unroll
                for (int u = 0; u < 4; ++u)
                    bfr[u] = *(const bf16x8*)((const char*)Bs[0] +
                            (wn + u * 16 + lm) * 128 + (((kh * 4 + lq) ^ lb) * 16));
                #pragma unroll
                for (int t = 0; t < 4; ++t)
                    #pragma unroll
                    for (int u = 0; u < 4; ++u)
                        acc[t][u] = __builtin_amdgcn_mfma_f32_16x16x32_bf16(
                            af[t], bfr[u], acc[t][u], 0, 0, 0);
            }
            __syncthreads();
        }
    }

    // ---- fused head3 epilogue: part[bnIdx][row] += gelu(p2_tile) @ w3
    if (FUSE_H3) {
        float w3c[4][3]; float bvv[4];
        #pragma unroll
        for (int u = 0; u < 4; ++u) {
            int col = bn + wn + u * 16 + lm;
            bool ok = (col < N);
            bvv[u]    = ok ? bias[col] : 0.f;
            w3c[u][0] = ok ? w3p[col * 3 + 0] : 0.f;
            w3c[u][1] = ok ? w3p[col * 3 + 1] : 0.f;
            w3c[u][2] = ok ? w3p[col * 3 + 2] : 0.f;
        }
        float* red = (float*)As;         // [4 waves][64 rows][3], 3 KB, As dead
        #pragma unroll
        for (int t = 0; t < 4; ++t) {
            #pragma unroll
            for (int r = 0; r < 4; ++r) {
                float s0 = 0.f, s1 = 0.f, s2 = 0.f;
                #pragma unroll
                for (int u = 0; u < 4; ++u) {
                    float v = gelu_f(acc[t][u][r] + bvv[u]);
                    s0 += v * w3c[u][0];
                    s1 += v * w3c[u][1];
                    s2 += v * w3c[u][2];
                }
                #pragma unroll
                for (int off = 8; off; off >>= 1) {
                    s0 += __shfl_xor(s0, off);
                    s1 += __shfl_xor(s1, off);
                    s2 += __shfl_xor(s2, off);
                }
                if (lm == 0) {
                    int lr = t * 16 + lq * 4 + r;            // 0..63 within wave
                    float* d = red + (wave * 64 + lr) * 3;
                    d[0] = s0; d[1] = s1; d[2] = s2;
                }
            }
        }
        __syncthreads();
        if ((wave & 1) == 0 && lane < 64) {       // waves 0,2 combine wn pair
            int lr = lane;
            int rowg = bm + wm + lr;
            float* a = red + ((wave + 0) * 64 + lr) * 3;
            float* b = red + ((wave + 1) * 64 + lr) * 3;
            float* d = partp + ((size_t)bnIdx * M + rowg) * 3;
            d[0] = a[0] + b[0];
            d[1] = a[1] + b[1];
            d[2] = a[2] + b[2];
        }
        return;
    }

    // ---- epilogue: C col = lane&15, row = quad*4 + reg (verified m89/m91)
    #pragma unroll
    for (int u = 0; u < 4; ++u) {
        int col = bn + wn + u * 16 + lm;
        if (col >= N) continue;
        float bv = HAS_BIAS ? bias[col] : 0.f;
        #pragma unroll
        for (int t = 0; t < 4; ++t) {
            #pragma unroll
            for (int r = 0; r < 4; ++r) {
                int rowg = bm + wm + t * 16 + lq * 4 + r;
                float v = acc[t][u][r] + bv;
                if (DO_GELU) v = gelu_f(v);
                if (OUT_F32) {
                    Cf[(size_t)rowg * N + col] = v;
                    if (Cb) Cb[(size_t)rowg * N + col] = f2u(v);  // dual write
                } else {
                    Cb[(size_t)rowg * N + col] = f2u(v);
                }
            }
        }
    }
}

// ---------------------------------------------------------------------------
// Partial reduce: pred[row_base+r,:] = b3 + sum_{s<4} part[s][r][:]
// ---------------------------------------------------------------------------
__global__ __launch_bounds__(256)
void red3_k(const float* __restrict__ part, const float* __restrict__ b3,
            float* __restrict__ out, int row_base, int Mr)
{
    int r = blockIdx.x * 256 + threadIdx.x;
    if (r >= Mr) return;
    float s0 = b3[0], s1 = b3[1], s2 = b3[2];
    #pragma unroll
    for (int s = 0; s < 4; ++s) {
        const float* p = part + ((size_t)s * Mr + r) * 3;
        s0 += p[0]; s1 += p[1]; s2 += p[2];
    }
    float* d = out + (size_t)FEAT_ELEMS + (size_t)(row_base + r) * 3;
    d[0] = s0; d[1] = s1; d[2] = s2;
}

// ---------------------------------------------------------------------------
// Pair fuse: p1[r,:] = gelu(U[src] + V[dst] + b1)  (distributed head GEMM1).
// UV bf16 [nodes][1600] = [U(800) | V(800)]. Flattened: 1 thread = one 8-elem
// chunk (row = idx/100 via magic div); no idle lanes. UV rows L3-resident.
// ---------------------------------------------------------------------------
__global__ __launch_bounds__(256)
void pair_fuse_k(const u16* __restrict__ UV, const float* __restrict__ b1,
                 const int* __restrict__ src0, const int* __restrict__ dst0,
                 u16* __restrict__ p1, int b0, int nrows)
{
    unsigned idx = blockIdx.x * 256u + threadIdx.x;
    unsigned total = (unsigned)nrows * 100u;
    if (idx >= total) return;
    unsigned r  = (unsigned)(((unsigned long long)idx * 1374389535ull) >> 37); // /100
    unsigned c8 = idx - r * 100u;
    int e = r & (E_ - 1);
    int gs, gd;
    if (b0 >= 0) {                        // big mode: global node ids
        int b = b0 + (int)(r >> 14);
        gs = (b << 10) + src0[e];
        gd = (b << 10) + dst0[e];
    } else {                              // small mode: per-batch UV table
        gs = src0[e]; gd = dst0[e];
    }
    uint4 qu = *(const uint4*)(UV + (size_t)gs * UVW_ + c8 * 8);
    uint4 qv = *(const uint4*)(UV + (size_t)gd * UVW_ + PAIR_ + c8 * 8);
    float4 bva = *(const float4*)(b1 + c8 * 8);
    float4 bvb = *(const float4*)(b1 + c8 * 8 + 4);
    float bb[8] = {bva.x, bva.y, bva.z, bva.w, bvb.x, bvb.y, bvb.z, bvb.w};
    unsigned int uu[4] = {qu.x, qu.y, qu.z, qu.w};
    unsigned int vv[4] = {qv.x, qv.y, qv.z, qv.w};
    uint4 o; unsigned int* op = (unsigned int*)&o;
    #pragma unroll
    for (int q = 0; q < 4; ++q) {
        float a0 = u2f((u16)(uu[q] & 0xffff)) + u2f((u16)(vv[q] & 0xffff)) + bb[2*q];
        float a1 = u2f((u16)(uu[q] >> 16))    + u2f((u16)(vv[q] >> 16))    + bb[2*q+1];
        op[q] = pack2(gelu_f(a0), gelu_f(a1));
    }
    *(uint4*)(p1 + (size_t)r * PAIR_ + c8 * 8) = o;
}

// ---------------------------------------------------------------------------
// Attention scores: a_s[n,h] = sum_f wh[n,h*200+f]*att_src[h*200+f]; same a_d.
// ---------------------------------------------------------------------------
__global__ __launch_bounds__(256)
void scores_k(const u16* __restrict__ wh, const float* __restrict__ att_s,
              const float* __restrict__ att_d, float* __restrict__ a_s,
              float* __restrict__ a_d)
{
    int n = blockIdx.x * 4 + (threadIdx.x >> 6);
    int lane = threadIdx.x & 63;
    const u16* row = wh + (size_t)n * OUT_;
    float as0 = 0, as1 = 0, ad0 = 0, ad1 = 0;
    for (int f = lane; f < OUT_; f += 64) {
        float v = u2f(row[f]);
        float s = att_s[f];
        float d = att_d[f];
        if (f < 200) { as0 += v * s; ad0 += v * d; }
        else         { as1 += v * s; ad1 += v * d; }
    }
    for (int off = 32; off; off >>= 1) {
        as0 += __shfl_xor(as0, off); as1 += __shfl_xor(as1, off);
        ad0 += __shfl_xor(ad0, off); ad1 += __shfl_xor(ad1, off);
    }
    if (lane == 0) {
        a_s[(size_t)n * 2 + 0] = as0; a_s[(size_t)n * 2 + 1] = as1;
        a_d[(size_t)n * 2 + 0] = ad0; a_d[(size_t)n * 2 + 1] = ad1;
    }
}

// ---------------------------------------------------------------------------
// CSR build (edges shared across batches; incl. self-loops)
// ---------------------------------------------------------------------------
__global__ void csr_count_k(const int* __restrict__ edges, int* __restrict__ deg)
{
    int et = blockIdx.x * blockDim.x + threadIdx.x;
    if (et >= ET_) return;
    int dst = (et < E_) ? edges[E_ + et] : (et - E_);
    atomicAdd(&deg[dst], 1);
}

__global__ __launch_bounds__(1024)
void csr_scan_k(const int* __restrict__ deg, int* __restrict__ row_ptr,
                int* __restrict__ cnt)
{
    __shared__ int s[1024];
    int t = threadIdx.x;
    int d = deg[t];
    s[t] = d;
    __syncthreads();
    for (int off = 1; off < 1024; off <<= 1) {
        int v = (t >= off) ? s[t - off] : 0;
        __syncthreads();
        s[t] += v;
        __syncthreads();
    }
    row_ptr[t] = s[t] - d;   // exclusive
    cnt[t] = s[t] - d;
    if (t == 1023) row_ptr[1024] = s[t];
}

__global__ void csr_fill_k(const int* __restrict__ edges, int* __restrict__ cnt,
                           int* __restrict__ col_src)
{
    int et = blockIdx.x * blockDim.x + threadIdx.x;
    if (et >= ET_) return;
    int src, dst;
    if (et < E_) { src = edges[et]; dst = edges[E_ + et]; }
    else         { src = et - E_;  dst = src; }
    int pos = atomicAdd(&cnt[dst], 1);
    col_src[pos] = src;
}

// ---------------------------------------------------------------------------
// Fused GAT softmax + aggregation + residual, in place on f32 feat (d_out).
// Vectorized: lane<50 handles 8 contiguous cols via uint4 wh loads; 4 j-slices
// (one per wave) reduced through padded LDS partials. Optionally emits bf16
// copy of feat (featb16) for the UV GEMM.
// ---------------------------------------------------------------------------
__global__ __launch_bounds__(256)
void gat_k(const u16* __restrict__ wh,
           const float* __restrict__ a_s, const float* __restrict__ a_d,
           const int* __restrict__ row_ptr, const int* __restrict__ col_src,
           const float* __restrict__ gat_b, float* __restrict__ feat,
           u16* __restrict__ featb16)
{
    int gn = blockIdx.x;                  // b*1024 + n
    int b = gn >> 10, n = gn & 1023;
    int tid = threadIdx.x;
    __shared__ float s_ee[2][MAXD];
    __shared__ int   s_src[MAXD];
    __shared__ float s_misc[6];           // m0,m1,invz0,invz1,ad0,ad1
    __shared__ float s_part[4][50][9];    // +1 pad col: spread banks
    int start = row_ptr[n];
    int deg = row_ptr[n + 1] - start;

    if (tid < 64) {
        int lane = tid;
        float ad0 = a_d[(size_t)gn * 2 + 0];
        float ad1 = a_d[(size_t)gn * 2 + 1];
        float m0 = -1e30f, m1 = -1e30f;
        for (int j = lane; j < deg; j += 64) {
            int gs = (b << 10) + col_src[start + j];
            float e0 = a_s[(size_t)gs * 2 + 0] + ad0; e0 = (e0 > 0.f) ? e0 : 0.2f * e0;
            float e1 = a_s[(size_t)gs * 2 + 1] + ad1; e1 = (e1 > 0.f) ? e1 : 0.2f * e1;
            if (j < MAXD) { s_ee[0][j] = e0; s_ee[1][j] = e1; s_src[j] = gs; }
            m0 = fmaxf(m0, e0); m1 = fmaxf(m1, e1);
        }
        for (int off = 32; off; off >>= 1) {
            m0 = fmaxf(m0, __shfl_xor(m0, off));
            m1 = fmaxf(m1, __shfl_xor(m1, off));
        }
        float z0 = 0.f, z1 = 0.f;
        for (int j = lane; j < deg; j += 64) {
            float e0, e1;
            if (j < MAXD) { e0 = s_ee[0][j]; e1 = s_ee[1][j]; }
            else {
                int gs = (b << 10) + col_src[start + j];
                e0 = a_s[(size_t)gs * 2 + 0] + ad0; e0 = (e0 > 0.f) ? e0 : 0.2f * e0;
                e1 = a_s[(size_t)gs * 2 + 1] + ad1; e1 = (e1 > 0.f) ? e1 : 0.2f * e1;
            }
            float t0 = __expf(e0 - m0), t1 = __expf(e1 - m1);
            if (j < MAXD) { s_ee[0][j] = t0; s_ee[1][j] = t1; }
            z0 += t0; z1 += t1;
        }
        for (int off = 32; off; off >>= 1) {
            z0 += __shfl_xor(z0, off);
            z1 += __shfl_xor(z1, off);
        }
        if (lane == 0) {
            s_misc[0] = m0; s_misc[1] = m1;
            s_misc[2] = (z0 > 0.f) ? 1.f / z0 : 0.f;
            s_misc[3] = (z1 > 0.f) ? 1.f / z1 : 0.f;
            s_misc[4] = ad0; s_misc[5] = ad1;
        }
    }
    __syncthreads();

    int wv = tid >> 6, ln = tid & 63;
    if (ln < 50) {
        int h = (ln >= 25);
        float m = s_misc[h], ad = s_misc[4 + h];
        float acc[8] = {};
        for (int j = wv; j < deg; j += 4) {
            float w; int gs;
            if (j < MAXD) { w = s_ee[h][j]; gs = s_src[j]; }
            else {
                gs = (b << 10) + col_src[start + j];
                float e = a_s[(size_t)gs * 2 + h] + ad;
                e = (e > 0.f) ? e : 0.2f * e;
                w = __expf(e - m);
            }
            uint4 q = *(const uint4*)(wh + (size_t)gs * OUT_ + ln * 8);
            acc[0] += w * u2f((u16)(q.x & 0xffff));
            acc[1] += w * u2f((u16)(q.x >> 16));
            acc[2] += w * u2f((u16)(q.y & 0xffff));
            acc[3] += w * u2f((u16)(q.y >> 16));
            acc[4] += w * u2f((u16)(q.z & 0xffff));
            acc[5] += w * u2f((u16)(q.z >> 16));
            acc[6] += w * u2f((u16)(q.w & 0xffff));
            acc[7] += w * u2f((u16)(q.w >> 16));
        }
        #pragma unroll
        for (int k = 0; k < 8; ++k) s_part[wv][ln][k] = acc[k];
    }
    __syncthreads();
    if (tid < 50) {
        int h = (tid >= 25);
        float iz = s_misc[2 + h];
        size_t base = (size_t)gn * OUT_ + tid * 8;
        float4 f0 = *(const float4*)(feat + base);
        float4 f1 = *(const float4*)(feat + base + 4);
        float fv[8] = { f0.x, f0.y, f0.z, f0.w, f1.x, f1.y, f1.z, f1.w };
        float o[8];
        #pragma unroll
        for (int k = 0; k < 8; ++k) {
            float s = s_part[0][tid][k] + s_part[1][tid][k] +
                      s_part[2][tid][k] + s_part[3][tid][k];
            o[k] = fv[k] + s * iz + gat_b[tid * 8 + k];
        }
        *(float4*)(feat + base)     = make_float4(o[0], o[1], o[2], o[3]);
        *(float4*)(feat + base + 4) = make_float4(o[4], o[5], o[6], o[7]);
        if (featb16) {
            uint4 bq;
            bq.x = pack2(o[0], o[1]); bq.y = pack2(o[2], o[3]);
            bq.z = pack2(o[4], o[5]); bq.w = pack2(o[6], o[7]);
            *(uint4*)(featb16 + base) = bq;
        }
    }
}

// ---------------------------------------------------------------------------
// Final tiny GEMM (small-mode only): pred[e,:] = p2[e,:] @ w3[400,3] + b3.
// ---------------------------------------------------------------------------
__global__ __launch_bounds__(256)
void head3_k(const u16* __restrict__ p2, const float* __restrict__ w3,
             const float* __restrict__ b3, float* __restrict__ out,
             int row_base, int nrows)
{
    int wv = threadIdx.x >> 6, lane = threadIdx.x & 63;
    float w3r[24];
    if (lane < 50) {
        #pragma unroll
        for (int q = 0; q < 6; ++q) {
            float4 v = *(const float4*)(w3 + lane * 24 + q * 4);
            w3r[q * 4 + 0] = v.x; w3r[q * 4 + 1] = v.y;
            w3r[q * 4 + 2] = v.z; w3r[q * 4 + 3] = v.w;
        }
    }
    int e0 = blockIdx.x * 16 + wv * 4;
    for (int ei = 0; ei < 4; ++ei) {
        int e = e0 + ei;
        if (e >= nrows) break;
        float s0 = 0, s1 = 0, s2 = 0;
        if (lane < 50) {
            uint4 q = *(const uint4*)(p2 + (size_t)e * OUT_ + lane * 8);
            float f[8];
            f[0] = u2f((u16)(q.x & 0xffff)); f[1] = u2f((u16)(q.x >> 16));
            f[2] = u2f((u16)(q.y & 0xffff)); f[3] = u2f((u16)(q.y >> 16));
            f[4] = u2f((u16)(q.z & 0xffff)); f[5] = u2f((u16)(q.z >> 16));
            f[6] = u2f((u16)(q.w & 0xffff)); f[7] = u2f((u16)(q.w >> 16));
            #pragma unroll
            for (int k = 0; k < 8; ++k) {
                s0 += f[k] * w3r[k * 3 + 0];
                s1 += f[k] * w3r[k * 3 + 1];
                s2 += f[k] * w3r[k * 3 + 2];
            }
        }
        for (int off = 32; off; off >>= 1) {
            s0 += __shfl_xor(s0, off);
            s1 += __shfl_xor(s1, off);
            s2 += __shfl_xor(s2, off);
        }
        if (lane == 0) {
            size_t o = (size_t)FEAT_ELEMS + (size_t)(row_base + e) * 3;
            out[o + 0] = s0 + b3[0];
            out[o + 1] = s1 + b3[1];
            out[o + 2] = s2 + b3[2];
        }
    }
}

extern "C" void kernel_launch(void* const* d_in, const int* in_sizes, int n_in,
                              void* d_out, int out_size, void* d_ws, size_t ws_size,
                              hipStream_t stream)
{
    const float* patch  = (const float*)d_in[0];
    const int*   edges  = (const int*)d_in[1];
    const float* enc_w1 = (const float*)d_in[2];
    const float* enc_b1 = (const float*)d_in[3];
    const float* enc_w2 = (const float*)d_in[4];
    const float* enc_b2 = (const float*)d_in[5];
    const float* gat_w  = (const float*)d_in[6];
    const float* att_s  = (const float*)d_in[7];
    const float* att_d  = (const float*)d_in[8];
    const float* gat_b  = (const float*)d_in[9];
    const float* h_w1   = (const float*)d_in[10];
    const float* h_b1   = (const float*)d_in[11];
    const float* h_w2   = (const float*)d_in[12];
    const float* h_b2   = (const float*)d_in[13];
    const float* h_w3   = (const float*)d_in[14];
    const float* h_b3   = (const float*)d_in[15];
    float* out  = (float*)d_out;
    float* feat = out;                          // f32 [32768,400] in d_out
    char*  ws   = (char*)d_ws;

    const int* src0 = edges;
    const int* dst0 = edges + E_;

    // --- mode select from ws_size (deterministic; graph-capture safe) ------
    // big-mode layout:
    //   [0,R0)                enc1 bf16 (33.5MB); featb16 overlays (dead enc1);
    //                         head-phase: part f32 [4][Mr][3] (3.1MB, CB=4)
    //   [R0, R0+26.2MB)       whb bf16            (dead after gat_k)
    //   [R0+26.2, R0+52.4MB)  encb16 bf16 (enc out, consumed by GAT linear)
    //   [R0, R0+UVSZ)         UV bf16 [32768,1600] (overlays whb+encb16, after)
    //   [R0+UVSZ, +CB*26.2MB) p1 chunk; patchb16 (50.3MB) overlays p1 early
    //   [ws_size-TAIL, ..)    weights + scores + CSR + zbuf
    // p2 eliminated (head3 fused into GEMM2 epilogue, non-atomic partials).
    // CB=4 keeps UV(105MB)+p1(105MB) L3-resident; CB>=2 needed for patchb16.
    const size_t R0 = 33554432ull, TAIL = 4194304ull;
    const size_t UVSZ = 104857600ull;           // 32768*1600*2
    const size_t P1SZ = 26214400ull;            // per-batch p1
    int CB = 0;
    if      (ws_size >= R0 + UVSZ + TAIL + 4 * P1SZ) CB = 4;
    else if (ws_size >= R0 + UVSZ + TAIL + 2 * P1SZ) CB = 2;
    const bool big = (CB >= 2);

    u16 *enc1, *whb, *p1, *p2, *featb16, *uv, *w1t, *w2t, *gwt, *uvwt, *hw2t;
    u16 *patchb16, *encb16;
    float *a_s, *a_d, *part; int *deg;
    if (big) {
        enc1    = (u16*)ws;
        featb16 = (u16*)ws;                     // overlays enc1 (dead)
        part    = (float*)ws;                   // head-phase reuse (featb16 dead)
        whb     = (u16*)(ws + R0);
        uv      = (u16*)(ws + R0);              // overlays whb (dead after gat)
        encb16  = (u16*)(ws + R0 + 26214400ull);// enc bf16, dead before UV GEMM
        p1      = (u16*)(ws + R0 + UVSZ);
        patchb16= (u16*)(ws + R0 + UVSZ);       // overlays p1 (dead before head)
        p2      = nullptr;
        size_t tb = (ws_size - TAIL) & ~(size_t)255;
        w1t  = (u16*)(ws + tb);
        w2t  = (u16*)(ws + tb + 786432);
        gwt  = (u16*)(ws + tb + 1196032);
        uvwt = (u16*)(ws + tb + 1516032);       // 1600*400*2 = 1,280,000
        hw2t = (u16*)(ws + tb + 2796032);
        a_s  = (float*)(ws + tb + 3436032);
        a_d  = (float*)(ws + tb + 3698176);
        deg  = (int*)(ws + tb + 3960320);
    } else {
        // small mode: per-batch loop; UV table is per-batch [1024,1600] bf16
        enc1    = (u16*)ws;                     // sequenced overlays
        whb     = (u16*)ws;
        p1      = (u16*)ws;
        featb16 = nullptr;
        patchb16= nullptr;
        encb16  = nullptr;
        part    = nullptr;
        p2      = (u16*)(ws + 26214400);
        uv      = (u16*)(ws + 39321600);        // 1024*1600*2 = 3,276,800
        w1t  = (u16*)(ws + 42598400);
        w2t  = (u16*)(ws + 43384832);
        gwt  = (u16*)(ws + 43794432);
        uvwt = (u16*)(ws + 44114432);
        hw2t = (u16*)(ws + 45394432);
        a_s  = (float*)(ws + 46034432);
        a_d  = (float*)(ws + 46296576);
        deg  = (int*)(ws + 46558720);
    }
    int* row_ptr = deg + 1024;
    int* cnt     = row_ptr + 1032;
    int* col_src = cnt + 1024;
    u16* zbuf = (u16*)(col_src + 17408);        // 256 B zero scratch (16B aligned)

    hipMemsetAsync(zbuf, 0, 256, stream);

    // weight transposes (bf16), tiny
    wt_k<<<(HID * IN_DIM + 255) / 256, 256, 0, stream>>>(enc_w1, w1t, IN_DIM, HID);
    wt_k<<<(OUT_ * HID + 255) / 256, 256, 0, stream>>>(enc_w2, w2t, HID, OUT_);
    wt_k<<<(OUT_ * OUT_ + 255) / 256, 256, 0, stream>>>(gat_w, gwt, OUT_, OUT_);
    wtuv_k<<<(UVW_ * OUT_ + 255) / 256, 256, 0, stream>>>(h_w1, uvwt);
    wt_k<<<(OUT_ * PAIR_ + 255) / 256, 256, 0, stream>>>(h_w2, hw2t, PAIR_, OUT_);

    // CSR by dst (batch-independent)
    hipMemsetAsync(deg, 0, 1024 * sizeof(int), stream);
    csr_count_k<<<(ET_ + 255) / 256, 256, 0, stream>>>(edges, deg);
    csr_scan_k<<<1, 1024, 0, stream>>>(deg, row_ptr, cnt);
    csr_fill_k<<<(ET_ + 255) / 256, 256, 0, stream>>>(edges, cnt, col_src);

    if (big) {
        // patch -> bf16 once (numerics identical: staging already cvt'd)
        f2b_k<<<(B_ * N_ * IN_DIM / 8 + 255) / 256, 256, 0, stream>>>(
            patch, patchb16, B_ * N_ * IN_DIM / 8);
        // encoder: enc1 = gelu(patch @ w1 + b1)
        mfma_gemm_k<1, true, true, false, false><<<dim3(HID / 128, (B_ * N_) / 128), 256, 0, stream>>>(
            nullptr, patchb16, w1t, enc_b1, enc1, nullptr, B_ * N_, HID, IN_DIM, zbuf,
            nullptr, nullptr);
        // feat(f32, d_out) + encb16(bf16) = enc1 @ w2 + b2
        mfma_gemm_k<1, false, true, true, false><<<dim3((OUT_ + 127) / 128, (B_ * N_) / 128), 256, 0, stream>>>(
            nullptr, enc1, w2t, enc_b2, encb16, feat, B_ * N_, OUT_, HID, zbuf,
            nullptr, nullptr);
        // GAT linear: wh = enc(bf16) @ gat_w
        mfma_gemm_k<1, false, false, false, false><<<dim3((OUT_ + 127) / 128, (B_ * N_) / 128), 256, 0, stream>>>(
            nullptr, encb16, gwt, nullptr, whb, nullptr, B_ * N_, OUT_, OUT_, zbuf,
            nullptr, nullptr);
    } else {
        mfma_gemm_k<0, true, true, false, false><<<dim3(HID / 128, (B_ * N_) / 128), 256, 0, stream>>>(
            patch, nullptr, w1t, enc_b1, enc1, nullptr, B_ * N_, HID, IN_DIM, zbuf,
            nullptr, nullptr);
        mfma_gemm_k<1, false, true, true, false><<<dim3((OUT_ + 127) / 128, (B_ * N_) / 128), 256, 0, stream>>>(
            nullptr, enc1, w2t, enc_b2, nullptr, feat, B_ * N_, OUT_, HID, zbuf,
            nullptr, nullptr);
        mfma_gemm_k<0, false, false, false, false><<<dim3((OUT_ + 127) / 128, (B_ * N_) / 128), 256, 0, stream>>>(
            feat, nullptr, gwt, nullptr, whb, nullptr, B_ * N_, OUT_, OUT_, zbuf,
            nullptr, nullptr);
    }

    scores_k<<<(B_ * N_) / 4, 256, 0, stream>>>(whb, att_s, att_d, a_s, a_d);
    gat_k<<<B_ * N_, 256, 0, stream>>>(whb, a_s, a_d, row_ptr, col_src,
                                       gat_b, feat, featb16);

    // predict head — head GEMM1 distributed over the pair-gather:
    //   pair @ h_w1 = feat[src] @ h_w1[0:400,:] + feat[dst] @ h_w1[400:800,:]
    //              = U[src] + V[dst]   (per-NODE GEMM: 32x less FLOP)
    // GEMM2's epilogue contracts p2 (in registers) with w3 -> 4 non-atomic
    // partial slices; red3_k reduces them into pred.
    if (big) {
        // UV = featb16 @ uvwt  -> bf16 [32768,1600]
        mfma_gemm_k<1, false, false, false, false><<<dim3((UVW_ + 127) / 128, (B_ * N_) / 128), 256, 0, stream>>>(
            nullptr, featb16, uvwt, nullptr, uv, nullptr, B_ * N_, UVW_, OUT_, zbuf,
            nullptr, nullptr);
        for (int b0 = 0; b0 < B_; b0 += CB) {
            int Mr = CB * E_;
            pair_fuse_k<<<(Mr * 100 + 255) / 256, 256, 0, stream>>>(
                uv, h_b1, src0, dst0, p1, b0, Mr);
            mfma_gemm_k<1, true, true, false, true><<<dim3((OUT_ + 127) / 128, Mr / 128), 256, 0, stream>>>(
                nullptr, p1, hw2t, h_b2, nullptr, nullptr, Mr, OUT_, PAIR_, zbuf,
                h_w3, part);
            red3_k<<<(Mr + 255) / 256, 256, 0, stream>>>(part, h_b3, out, b0 * E_, Mr);
        }
    } else {
        for (int b = 0; b < B_; ++b) {
            const float* featb = feat + (size_t)b * N_ * OUT_;
            mfma_gemm_k<0, false, false, false, false><<<dim3((UVW_ + 127) / 128, N_ / 128), 256, 0, stream>>>(
                featb, nullptr, uvwt, nullptr, uv, nullptr, N_, UVW_, OUT_, zbuf,
                nullptr, nullptr);
            pair_fuse_k<<<(E_ * 100 + 255) / 256, 256, 0, stream>>>(
                uv, h_b1, src0, dst0, p1, -1, E_);
            mfma_gemm_k<1, true, true, false, false><<<dim3((OUT_ + 127) / 128, E_ / 128), 256, 0, stream>>>(
                nullptr, p1, hw2t, h_b2, p2, nullptr, E_, OUT_, PAIR_, zbuf,
                nullptr, nullptr);
            head3_k<<<(E_ + 15) / 16, 256, 0, stream>>>(p2, h_w3, h_b3, out,
                                                        b * E_, E_);
        }
    }
}

// Round 6
// 1502.006 us; speedup vs baseline: 1.4582x; 1.0861x over previous
//
#include <hip/hip_runtime.h>
#include <hip/hip_bf16.h>

typedef unsigned short u16;   // bf16 bits
typedef __attribute__((ext_vector_type(8))) short bf16x8;   // MFMA A/B frag
typedef __attribute__((ext_vector_type(4))) float f32x4;    // MFMA C/D frag

#define B_   32
#define N_   1024
#define E_   16384
#define ET_  17408            // E_ + N_ self-loops
#define IN_DIM 768
#define HID  512
#define OUT_ 400
#define PAIR_ 800
#define UVW_ 1600             // U(800) ++ V(800) per node
#define FEAT_ELEMS 13107200   // B_*N_*OUT_
#define MAXD 128

__device__ __forceinline__ float u2f(u16 u) {
    union { unsigned int i; float f; } v; v.i = ((unsigned int)u) << 16; return v.f;
}
__device__ __forceinline__ u16 f2u(float f) {
    __hip_bfloat16 h = __float2bfloat16(f);   // RNE, HW cvt on gfx950
    return *(u16*)&h;
}
__device__ __forceinline__ unsigned int pack2(float a, float b) {
    return (unsigned int)f2u(a) | ((unsigned int)f2u(b) << 16);
}

__device__ __forceinline__ float gelu_f(float x) {
    const float c = 0.7978845608028654f;          // sqrt(2/pi)
    float u = c * (x + 0.044715f * x * x * x);
    float t = 2.0f / (1.0f + __expf(-2.0f * u)) - 1.0f;   // tanh(u), overflow-safe
    return 0.5f * x * (1.0f + t);
}

// async global->LDS, 16 B per lane; LDS dest is wave-uniform base + lane*16
__device__ __forceinline__ void load_lds16(const void* g, void* l) {
    __builtin_amdgcn_global_load_lds(
        (const __attribute__((address_space(1))) void*)g,
        (__attribute__((address_space(3))) void*)l, 16, 0, 0);
}

// ---------------------------------------------------------------------------
// Weight transpose + bf16 convert: Wt[n][k] = bf16(W[k][n]). Tiny, once/launch.
// ---------------------------------------------------------------------------
__global__ void wt_k(const float* __restrict__ W, u16* __restrict__ Wt,
                     int K, int N)
{
    int i = blockIdx.x * 256 + threadIdx.x;
    if (i >= N * K) return;
    int n = i / K, k = i - n * K;
    Wt[i] = f2u(W[(size_t)k * N + n]);
}

// h_w1 [800][800] -> uvwt [1600][400] bf16 (transposed, halves split)
__global__ void wtuv_k(const float* __restrict__ W, u16* __restrict__ Wt)
{
    int i = blockIdx.x * 256 + threadIdx.x;       // over 1600*400
    if (i >= UVW_ * OUT_) return;
    int n = i / OUT_, k = i - n * OUT_;
    int row = (n >= PAIR_) ? OUT_ + k : k;
    int col = (n >= PAIR_) ? n - PAIR_ : n;
    Wt[i] = f2u(W[(size_t)row * PAIR_ + col]);
}

// f32 -> bf16 bulk convert, 8 elems/lane
__global__ void f2b_k(const float* __restrict__ X, u16* __restrict__ Y, int n8)
{
    int i = blockIdx.x * 256 + threadIdx.x;
    if (i >= n8) return;
    const float4* p = (const float4*)X + (size_t)i * 2;
    float4 a = p[0], b = p[1];
    uint4 o;
    o.x = pack2(a.x, a.y); o.y = pack2(a.z, a.w);
    o.z = pack2(b.x, b.y); o.w = pack2(b.z, b.w);
    ((uint4*)Y)[i] = o;
}

// ---------------------------------------------------------------------------
// MFMA GEMM: C[M,N] = act(A[M,K] @ W[K,N] + bias), f32 accumulate.
// WIDE=0: 128x128 tile, 4 waves (256 thr), each 64x64. (small-mode legacy)
// WIDE=1: 256x256 tile, 8 waves (512 thr), each 64x128 (acc[4][8]=128 VGPR).
//   Rationale (r5 post-mortem): 2-phase wall is per-barrier-window overhead;
//   wide doubles MFMA per window per SIMD (320->640 cyc), halves windows per
//   output row and halves A re-reads (gx 4->2 for N=512). LDS 2x64KB=128KB
//   (same as m201 template), __launch_bounds__(512,2) caps VGPR at 256.
// 2-phase pipeline: stage(next) BEFORE compute; s_waitcnt vmcnt(8) counted
// (8 loads/wave/stage in both modes); raw s_barrier pair per window.
// T1 XCD-chunked bijective swizzle (m204) for L2 locality of A panels.
// FUSE_H3: no C store; contract tile with w3 [N][3] after gelu(.+bias):
// shfl over lm, LDS-combine wn-wave pairs, non-atomic part[bnIdx][row][3];
// red3_k sums gx slices + b3 (r3 atomic version was 48MB write-through).
// LDS XOR swizzle phys_chunk=log_chunk^(row&7): global_load_lds contiguity
// AND conflict-free ds_read_b128 (m136). OOB lanes read zbuf.
// ---------------------------------------------------------------------------
template<int ASRC, bool DO_GELU, bool HAS_BIAS, bool OUT_F32, bool FUSE_H3, bool WIDE>
__global__ __launch_bounds__(WIDE ? 512 : 256, 2)
void mfma_gemm_k(const float* __restrict__ Af, const u16* __restrict__ Ab,
                 const u16* __restrict__ Wt, const float* __restrict__ bias,
                 u16* __restrict__ Cb, float* __restrict__ Cf,
                 int M, int N, int K,
                 const u16* __restrict__ zbuf,
                 const float* __restrict__ w3p, float* __restrict__ partp)
{
    static_assert(!WIDE || ASRC == 1, "wide path requires bf16 async staging");
    constexpr int BM  = WIDE ? 256 : 128;   // rows per block
    constexpr int BN  = WIDE ? 256 : 128;   // cols per block
    constexpr int NWV = WIDE ? 8 : 4;       // waves per block
    constexpr int UN  = WIDE ? 8 : 4;       // 16-col fragments per wave
    constexpr int WNS = WIDE ? 128 : 64;    // per-wave col span

    __shared__ __align__(16) u16 As[2][BM * 64];
    __shared__ __align__(16) u16 Bs[2][BN * 64];
    const int tid  = threadIdx.x;
    // --- T1 bijective XCD swizzle ---
    const int gx   = gridDim.x;
    const int nwg  = gx * gridDim.y;
    const int orig = blockIdx.y * gx + blockIdx.x;
    const int qc   = nwg >> 3, rc = nwg & 7;
    const int xcd  = orig & 7, lid = orig >> 3;
    const int wg   = ((xcd < rc) ? xcd * (qc + 1) : rc * (qc + 1) + (xcd - rc) * qc) + lid;
    const int bnIdx= wg % gx;
    const int bm   = (wg / gx) * BM;
    const int bn   = bnIdx * BN;
    const int wave = tid >> 6;
    const int lane = tid & 63;
    const int wm   = (wave >> 1) * 64;      // row group (both modes)
    const int wn   = (wave & 1) * WNS;      // col group
    const int lm   = lane & 15;
    const int lq   = lane >> 4;
    const int lb   = lm & 7;
    // async-staging lane geometry: instr c4 covers rows wave*32+c4*8 .. +7
    const int l8 = lane >> 3;            // row within 8-row group
    const int cl = (lane & 7) ^ l8;      // logical 8-elem chunk for this lane

    // per-c4 row metadata (wave*32 row groups cover BM = NWV*32 rows)
    size_t arow[4]; size_t brow[4]; bool bok[4];
    #pragma unroll
    for (int c4 = 0; c4 < 4; ++c4) {
        int rt = wave * 32 + c4 * 8 + l8;          // tile row 0..BM-1
        if (ASRC == 1) arow[c4] = (size_t)(bm + rt) * K;
        int n = bn + rt;
        bok[c4] = (n < N);
        brow[c4] = (size_t)(n < N ? n : 0) * K;
    }
    // VGPR-staging geometry (ASRC 0, narrow only)
    const int vrow = tid >> 1, vhalf = tid & 1;

    f32x4 acc[4][UN] = {};
    const int NT = (K + 63) >> 6;

    if (ASRC == 1) {
        auto stage = [&](int buf, int k0) {
            int kk = k0 + cl * 8;
            #pragma unroll
            for (int c4 = 0; c4 < 4; ++c4) {
                const u16* ga = (kk < K) ? Ab + arow[c4] + kk : zbuf;
                load_lds16(ga, (char*)As[buf] + (wave * 32 + c4 * 8) * 128);
            }
            #pragma unroll
            for (int c4 = 0; c4 < 4; ++c4) {
                const u16* gb = (bok[c4] && kk < K) ? Wt + brow[c4] + kk : zbuf;
                load_lds16(gb, (char*)Bs[buf] + (wave * 32 + c4 * 8) * 128);
            }
        };
        stage(0, 0);
        int cur = 0;
        for (int it = 0; it < NT; ++it) {
            const bool last = (it == NT - 1);
            if (!last) stage(cur ^ 1, (it + 1) * 64);
            if (!last) asm volatile("s_waitcnt vmcnt(8)" ::: "memory");
            else       asm volatile("s_waitcnt vmcnt(0)" ::: "memory");
            __builtin_amdgcn_s_barrier();
            const char* Abase = (const char*)As[cur];
            const char* Bbase = (const char*)Bs[cur];
            #pragma unroll
            for (int kh = 0; kh < 2; ++kh) {
                bf16x8 af[4], bfr[UN];
                #pragma unroll
                for (int t = 0; t < 4; ++t)
                    af[t] = *(const bf16x8*)(Abase +
                            (wm + t * 16 + lm) * 128 + (((kh * 4 + lq) ^ lb) * 16));
                #pragma unroll
                for (int u = 0; u < UN; ++u)
                    bfr[u] = *(const bf16x8*)(Bbase +
                            (wn + u * 16 + lm) * 128 + (((kh * 4 + lq) ^ lb) * 16));
                #pragma unroll
                for (int t = 0; t < 4; ++t)
                    #pragma unroll
                    for (int u = 0; u < UN; ++u)
                        acc[t][u] = __builtin_amdgcn_mfma_f32_16x16x32_bf16(
                            af[t], bfr[u], acc[t][u], 0, 0, 0);
            }
            asm volatile("" ::: "memory");
            __builtin_amdgcn_s_barrier();
            cur ^= 1;
        }
    } else {
        for (int k0 = 0; k0 < K; k0 += 64) {
            // ---- stage A (VGPR cvt, narrow only)
            #pragma unroll
            for (int c = 0; c < 4; ++c) {
                int c_log = vhalf * 4 + c;
                int kk = k0 + c_log * 8;
                uint4 wv = make_uint4(0, 0, 0, 0);
                if (kk < K) {
                    const float* p = Af + (size_t)(bm + vrow) * K + kk;
                    float4 v0 = *(const float4*)p;
                    float4 v1 = *(const float4*)(p + 4);
                    wv.x = pack2(v0.x, v0.y); wv.y = pack2(v0.z, v0.w);
                    wv.z = pack2(v1.x, v1.y); wv.w = pack2(v1.z, v1.w);
                }
                int pc = c_log ^ (vrow & 7);
                *(uint4*)((char*)As[0] + vrow * 128 + pc * 16) = wv;
            }
            // ---- stage B (async)
            {
                int kk = k0 + cl * 8;
                #pragma unroll
                for (int c4 = 0; c4 < 4; ++c4) {
                    const u16* gb = (bok[c4] && kk < K) ? Wt + brow[c4] + kk : zbuf;
                    load_lds16(gb, (char*)Bs[0] + (wave * 32 + c4 * 8) * 128);
                }
            }
            __syncthreads();
            #pragma unroll
            for (int kh = 0; kh < 2; ++kh) {
                bf16x8 af[4], bfr[UN];
                #pragma unroll
                for (int t = 0; t < 4; ++t)
                    af[t] = *(const bf16x8*)((const char*)As[0] +
                            (wm + t * 16 + lm) * 128 + (((kh * 4 + lq) ^ lb) * 16));
                #pragma unroll
                for (int u = 0; u < UN; ++u)
                    bfr[u] = *(const bf16x8*)((const char*)Bs[0] +
                            (wn + u * 16 + lm) * 128 + (((kh * 4 + lq) ^ lb) * 16));
                #pragma unroll
                for (int t = 0; t < 4; ++t)
                    #pragma unroll
                    for (int u = 0; u < UN; ++u)
                        acc[t][u] = __builtin_amdgcn_mfma_f32_16x16x32_bf16(
                            af[t], bfr[u], acc[t][u], 0, 0, 0);
            }
            __syncthreads();
        }
    }

    // ---- fused head3 epilogue: part[bnIdx][row] = gelu(p2_tile) @ w3
    if (FUSE_H3) {
        float w3c[UN][3]; float bvv[UN];
        #pragma unroll
        for (int u = 0; u < UN; ++u) {
            int col = bn + wn + u * 16 + lm;
            bool ok = (col < N);
            bvv[u]    = ok ? bias[col] : 0.f;
            w3c[u][0] = ok ? w3p[col * 3 + 0] : 0.f;
            w3c[u][1] = ok ? w3p[col * 3 + 1] : 0.f;
            w3c[u][2] = ok ? w3p[col * 3 + 2] : 0.f;
        }
        float* red = (float*)As;         // [NWV][64 rows][3] floats, As dead
        #pragma unroll
        for (int t = 0; t < 4; ++t) {
            #pragma unroll
            for (int r = 0; r < 4; ++r) {
                float s0 = 0.f, s1 = 0.f, s2 = 0.f;
                #pragma unroll
                for (int u = 0; u < UN; ++u) {
                    float v = gelu_f(acc[t][u][r] + bvv[u]);
                    s0 += v * w3c[u][0];
                    s1 += v * w3c[u][1];
                    s2 += v * w3c[u][2];
                }
                #pragma unroll
                for (int off = 8; off; off >>= 1) {
                    s0 += __shfl_xor(s0, off);
                    s1 += __shfl_xor(s1, off);
                    s2 += __shfl_xor(s2, off);
                }
                if (lm == 0) {
                    int lr = t * 16 + lq * 4 + r;            // 0..63 within wave
                    float* d = red + (wave * 64 + lr) * 3;
                    d[0] = s0; d[1] = s1; d[2] = s2;
                }
            }
        }
        __syncthreads();
        if ((wave & 1) == 0) {            // even waves combine their wn pair
            int lr = lane;
            int rowg = bm + wm + lr;
            float* a = red + ((wave + 0) * 64 + lr) * 3;
            float* b = red + ((wave + 1) * 64 + lr) * 3;
            float* d = partp + ((size_t)bnIdx * M + rowg) * 3;
            d[0] = a[0] + b[0];
            d[1] = a[1] + b[1];
            d[2] = a[2] + b[2];
        }
        return;
    }

    // ---- epilogue: C col = lane&15, row = quad*4 + reg (verified m89/m91)
    #pragma unroll
    for (int u = 0; u < UN; ++u) {
        int col = bn + wn + u * 16 + lm;
        if (col >= N) continue;
        float bv = HAS_BIAS ? bias[col] : 0.f;
        #pragma unroll
        for (int t = 0; t < 4; ++t) {
            #pragma unroll
            for (int r = 0; r < 4; ++r) {
                int rowg = bm + wm + t * 16 + lq * 4 + r;
                float v = acc[t][u][r] + bv;
                if (DO_GELU) v = gelu_f(v);
                if (OUT_F32) {
                    Cf[(size_t)rowg * N + col] = v;
                    if (Cb) Cb[(size_t)rowg * N + col] = f2u(v);  // dual write
                } else {
                    Cb[(size_t)rowg * N + col] = f2u(v);
                }
            }
        }
    }
}

// ---------------------------------------------------------------------------
// Partial reduce: pred[row_base+r,:] = b3 + sum_{s<ns} part[s][r][:]
// ---------------------------------------------------------------------------
__global__ __launch_bounds__(256)
void red3_k(const float* __restrict__ part, const float* __restrict__ b3,
            float* __restrict__ out, int row_base, int Mr, int ns)
{
    int r = blockIdx.x * 256 + threadIdx.x;
    if (r >= Mr) return;
    float s0 = b3[0], s1 = b3[1], s2 = b3[2];
    for (int s = 0; s < ns; ++s) {
        const float* p = part + ((size_t)s * Mr + r) * 3;
        s0 += p[0]; s1 += p[1]; s2 += p[2];
    }
    float* d = out + (size_t)FEAT_ELEMS + (size_t)(row_base + r) * 3;
    d[0] = s0; d[1] = s1; d[2] = s2;
}

// ---------------------------------------------------------------------------
// Pair fuse: p1[r,:] = gelu(U[src] + V[dst] + b1)  (distributed head GEMM1).
// ---------------------------------------------------------------------------
__global__ __launch_bounds__(256)
void pair_fuse_k(const u16* __restrict__ UV, const float* __restrict__ b1,
                 const int* __restrict__ src0, const int* __restrict__ dst0,
                 u16* __restrict__ p1, int b0, int nrows)
{
    unsigned idx = blockIdx.x * 256u + threadIdx.x;
    unsigned total = (unsigned)nrows * 100u;
    if (idx >= total) return;
    unsigned r  = (unsigned)(((unsigned long long)idx * 1374389535ull) >> 37); // /100
    unsigned c8 = idx - r * 100u;
    int e = r & (E_ - 1);
    int gs, gd;
    if (b0 >= 0) {                        // big mode: global node ids
        int b = b0 + (int)(r >> 14);
        gs = (b << 10) + src0[e];
        gd = (b << 10) + dst0[e];
    } else {                              // small mode: per-batch UV table
        gs = src0[e]; gd = dst0[e];
    }
    uint4 qu = *(const uint4*)(UV + (size_t)gs * UVW_ + c8 * 8);
    uint4 qv = *(const uint4*)(UV + (size_t)gd * UVW_ + PAIR_ + c8 * 8);
    float4 bva = *(const float4*)(b1 + c8 * 8);
    float4 bvb = *(const float4*)(b1 + c8 * 8 + 4);
    float bb[8] = {bva.x, bva.y, bva.z, bva.w, bvb.x, bvb.y, bvb.z, bvb.w};
    unsigned int uu[4] = {qu.x, qu.y, qu.z, qu.w};
    unsigned int vv[4] = {qv.x, qv.y, qv.z, qv.w};
    uint4 o; unsigned int* op = (unsigned int*)&o;
    #pragma unroll
    for (int q = 0; q < 4; ++q) {
        float a0 = u2f((u16)(uu[q] & 0xffff)) + u2f((u16)(vv[q] & 0xffff)) + bb[2*q];
        float a1 = u2f((u16)(uu[q] >> 16))    + u2f((u16)(vv[q] >> 16))    + bb[2*q+1];
        op[q] = pack2(gelu_f(a0), gelu_f(a1));
    }
    *(uint4*)(p1 + (size_t)r * PAIR_ + c8 * 8) = o;
}

// ---------------------------------------------------------------------------
// Attention scores
// ---------------------------------------------------------------------------
__global__ __launch_bounds__(256)
void scores_k(const u16* __restrict__ wh, const float* __restrict__ att_s,
              const float* __restrict__ att_d, float* __restrict__ a_s,
              float* __restrict__ a_d)
{
    int n = blockIdx.x * 4 + (threadIdx.x >> 6);
    int lane = threadIdx.x & 63;
    const u16* row = wh + (size_t)n * OUT_;
    float as0 = 0, as1 = 0, ad0 = 0, ad1 = 0;
    for (int f = lane; f < OUT_; f += 64) {
        float v = u2f(row[f]);
        float s = att_s[f];
        float d = att_d[f];
        if (f < 200) { as0 += v * s; ad0 += v * d; }
        else         { as1 += v * s; ad1 += v * d; }
    }
    for (int off = 32; off; off >>= 1) {
        as0 += __shfl_xor(as0, off); as1 += __shfl_xor(as1, off);
        ad0 += __shfl_xor(ad0, off); ad1 += __shfl_xor(ad1, off);
    }
    if (lane == 0) {
        a_s[(size_t)n * 2 + 0] = as0; a_s[(size_t)n * 2 + 1] = as1;
        a_d[(size_t)n * 2 + 0] = ad0; a_d[(size_t)n * 2 + 1] = ad1;
    }
}

// ---------------------------------------------------------------------------
// CSR build (edges shared across batches; incl. self-loops)
// ---------------------------------------------------------------------------
__global__ void csr_count_k(const int* __restrict__ edges, int* __restrict__ deg)
{
    int et = blockIdx.x * blockDim.x + threadIdx.x;
    if (et >= ET_) return;
    int dst = (et < E_) ? edges[E_ + et] : (et - E_);
    atomicAdd(&deg[dst], 1);
}

__global__ __launch_bounds__(1024)
void csr_scan_k(const int* __restrict__ deg, int* __restrict__ row_ptr,
                int* __restrict__ cnt)
{
    __shared__ int s[1024];
    int t = threadIdx.x;
    int d = deg[t];
    s[t] = d;
    __syncthreads();
    for (int off = 1; off < 1024; off <<= 1) {
        int v = (t >= off) ? s[t - off] : 0;
        __syncthreads();
        s[t] += v;
        __syncthreads();
    }
    row_ptr[t] = s[t] - d;   // exclusive
    cnt[t] = s[t] - d;
    if (t == 1023) row_ptr[1024] = s[t];
}

__global__ void csr_fill_k(const int* __restrict__ edges, int* __restrict__ cnt,
                           int* __restrict__ col_src)
{
    int et = blockIdx.x * blockDim.x + threadIdx.x;
    if (et >= ET_) return;
    int src, dst;
    if (et < E_) { src = edges[et]; dst = edges[E_ + et]; }
    else         { src = et - E_;  dst = src; }
    int pos = atomicAdd(&cnt[dst], 1);
    col_src[pos] = src;
}

// ---------------------------------------------------------------------------
// Fused GAT softmax + aggregation + residual, in place on f32 feat (d_out).
// ---------------------------------------------------------------------------
__global__ __launch_bounds__(256)
void gat_k(const u16* __restrict__ wh,
           const float* __restrict__ a_s, const float* __restrict__ a_d,
           const int* __restrict__ row_ptr, const int* __restrict__ col_src,
           const float* __restrict__ gat_b, float* __restrict__ feat,
           u16* __restrict__ featb16)
{
    int gn = blockIdx.x;                  // b*1024 + n
    int b = gn >> 10, n = gn & 1023;
    int tid = threadIdx.x;
    __shared__ float s_ee[2][MAXD];
    __shared__ int   s_src[MAXD];
    __shared__ float s_misc[6];           // m0,m1,invz0,invz1,ad0,ad1
    __shared__ float s_part[4][50][9];    // +1 pad col: spread banks
    int start = row_ptr[n];
    int deg = row_ptr[n + 1] - start;

    if (tid < 64) {
        int lane = tid;
        float ad0 = a_d[(size_t)gn * 2 + 0];
        float ad1 = a_d[(size_t)gn * 2 + 1];
        float m0 = -1e30f, m1 = -1e30f;
        for (int j = lane; j < deg; j += 64) {
            int gs = (b << 10) + col_src[start + j];
            float e0 = a_s[(size_t)gs * 2 + 0] + ad0; e0 = (e0 > 0.f) ? e0 : 0.2f * e0;
            float e1 = a_s[(size_t)gs * 2 + 1] + ad1; e1 = (e1 > 0.f) ? e1 : 0.2f * e1;
            if (j < MAXD) { s_ee[0][j] = e0; s_ee[1][j] = e1; s_src[j] = gs; }
            m0 = fmaxf(m0, e0); m1 = fmaxf(m1, e1);
        }
        for (int off = 32; off; off >>= 1) {
            m0 = fmaxf(m0, __shfl_xor(m0, off));
            m1 = fmaxf(m1, __shfl_xor(m1, off));
        }
        float z0 = 0.f, z1 = 0.f;
        for (int j = lane; j < deg; j += 64) {
            float e0, e1;
            if (j < MAXD) { e0 = s_ee[0][j]; e1 = s_ee[1][j]; }
            else {
                int gs = (b << 10) + col_src[start + j];
                e0 = a_s[(size_t)gs * 2 + 0] + ad0; e0 = (e0 > 0.f) ? e0 : 0.2f * e0;
                e1 = a_s[(size_t)gs * 2 + 1] + ad1; e1 = (e1 > 0.f) ? e1 : 0.2f * e1;
            }
            float t0 = __expf(e0 - m0), t1 = __expf(e1 - m1);
            if (j < MAXD) { s_ee[0][j] = t0; s_ee[1][j] = t1; }
            z0 += t0; z1 += t1;
        }
        for (int off = 32; off; off >>= 1) {
            z0 += __shfl_xor(z0, off);
            z1 += __shfl_xor(z1, off);
        }
        if (lane == 0) {
            s_misc[0] = m0; s_misc[1] = m1;
            s_misc[2] = (z0 > 0.f) ? 1.f / z0 : 0.f;
            s_misc[3] = (z1 > 0.f) ? 1.f / z1 : 0.f;
            s_misc[4] = ad0; s_misc[5] = ad1;
        }
    }
    __syncthreads();

    int wv = tid >> 6, ln = tid & 63;
    if (ln < 50) {
        int h = (ln >= 25);
        float m = s_misc[h], ad = s_misc[4 + h];
        float acc[8] = {};
        for (int j = wv; j < deg; j += 4) {
            float w; int gs;
            if (j < MAXD) { w = s_ee[h][j]; gs = s_src[j]; }
            else {
                gs = (b << 10) + col_src[start + j];
                float e = a_s[(size_t)gs * 2 + h] + ad;
                e = (e > 0.f) ? e : 0.2f * e;
                w = __expf(e - m);
            }
            uint4 q = *(const uint4*)(wh + (size_t)gs * OUT_ + ln * 8);
            acc[0] += w * u2f((u16)(q.x & 0xffff));
            acc[1] += w * u2f((u16)(q.x >> 16));
            acc[2] += w * u2f((u16)(q.y & 0xffff));
            acc[3] += w * u2f((u16)(q.y >> 16));
            acc[4] += w * u2f((u16)(q.z & 0xffff));
            acc[5] += w * u2f((u16)(q.z >> 16));
            acc[6] += w * u2f((u16)(q.w & 0xffff));
            acc[7] += w * u2f((u16)(q.w >> 16));
        }
        #pragma unroll
        for (int k = 0; k < 8; ++k) s_part[wv][ln][k] = acc[k];
    }
    __syncthreads();
    if (tid < 50) {
        int h = (tid >= 25);
        float iz = s_misc[2 + h];
        size_t base = (size_t)gn * OUT_ + tid * 8;
        float4 f0 = *(const float4*)(feat + base);
        float4 f1 = *(const float4*)(feat + base + 4);
        float fv[8] = { f0.x, f0.y, f0.z, f0.w, f1.x, f1.y, f1.z, f1.w };
        float o[8];
        #pragma unroll
        for (int k = 0; k < 8; ++k) {
            float s = s_part[0][tid][k] + s_part[1][tid][k] +
                      s_part[2][tid][k] + s_part[3][tid][k];
            o[k] = fv[k] + s * iz + gat_b[tid * 8 + k];
        }
        *(float4*)(feat + base)     = make_float4(o[0], o[1], o[2], o[3]);
        *(float4*)(feat + base + 4) = make_float4(o[4], o[5], o[6], o[7]);
        if (featb16) {
            uint4 bq;
            bq.x = pack2(o[0], o[1]); bq.y = pack2(o[2], o[3]);
            bq.z = pack2(o[4], o[5]); bq.w = pack2(o[6], o[7]);
            *(uint4*)(featb16 + base) = bq;
        }
    }
}

// ---------------------------------------------------------------------------
// Final tiny GEMM (small-mode only): pred[e,:] = p2[e,:] @ w3[400,3] + b3.
// ---------------------------------------------------------------------------
__global__ __launch_bounds__(256)
void head3_k(const u16* __restrict__ p2, const float* __restrict__ w3,
             const float* __restrict__ b3, float* __restrict__ out,
             int row_base, int nrows)
{
    int wv = threadIdx.x >> 6, lane = threadIdx.x & 63;
    float w3r[24];
    if (lane < 50) {
        #pragma unroll
        for (int q = 0; q < 6; ++q) {
            float4 v = *(const float4*)(w3 + lane * 24 + q * 4);
            w3r[q * 4 + 0] = v.x; w3r[q * 4 + 1] = v.y;
            w3r[q * 4 + 2] = v.z; w3r[q * 4 + 3] = v.w;
        }
    }
    int e0 = blockIdx.x * 16 + wv * 4;
    for (int ei = 0; ei < 4; ++ei) {
        int e = e0 + ei;
        if (e >= nrows) break;
        float s0 = 0, s1 = 0, s2 = 0;
        if (lane < 50) {
            uint4 q = *(const uint4*)(p2 + (size_t)e * OUT_ + lane * 8);
            float f[8];
            f[0] = u2f((u16)(q.x & 0xffff)); f[1] = u2f((u16)(q.x >> 16));
            f[2] = u2f((u16)(q.y & 0xffff)); f[3] = u2f((u16)(q.y >> 16));
            f[4] = u2f((u16)(q.z & 0xffff)); f[5] = u2f((u16)(q.z >> 16));
            f[6] = u2f((u16)(q.w & 0xffff)); f[7] = u2f((u16)(q.w >> 16));
            #pragma unroll
            for (int k = 0; k < 8; ++k) {
                s0 += f[k] * w3r[k * 3 + 0];
                s1 += f[k] * w3r[k * 3 + 1];
                s2 += f[k] * w3r[k * 3 + 2];
            }
        }
        for (int off = 32; off; off >>= 1) {
            s0 += __shfl_xor(s0, off);
            s1 += __shfl_xor(s1, off);
            s2 += __shfl_xor(s2, off);
        }
        if (lane == 0) {
            size_t o = (size_t)FEAT_ELEMS + (size_t)(row_base + e) * 3;
            out[o + 0] = s0 + b3[0];
            out[o + 1] = s1 + b3[1];
            out[o + 2] = s2 + b3[2];
        }
    }
}

extern "C" void kernel_launch(void* const* d_in, const int* in_sizes, int n_in,
                              void* d_out, int out_size, void* d_ws, size_t ws_size,
                              hipStream_t stream)
{
    const float* patch  = (const float*)d_in[0];
    const int*   edges  = (const int*)d_in[1];
    const float* enc_w1 = (const float*)d_in[2];
    const float* enc_b1 = (const float*)d_in[3];
    const float* enc_w2 = (const float*)d_in[4];
    const float* enc_b2 = (const float*)d_in[5];
    const float* gat_w  = (const float*)d_in[6];
    const float* att_s  = (const float*)d_in[7];
    const float* att_d  = (const float*)d_in[8];
    const float* gat_b  = (const float*)d_in[9];
    const float* h_w1   = (const float*)d_in[10];
    const float* h_b1   = (const float*)d_in[11];
    const float* h_w2   = (const float*)d_in[12];
    const float* h_b2   = (const float*)d_in[13];
    const float* h_w3   = (const float*)d_in[14];
    const float* h_b3   = (const float*)d_in[15];
    float* out  = (float*)d_out;
    float* feat = out;                          // f32 [32768,400] in d_out
    char*  ws   = (char*)d_ws;

    const int* src0 = edges;
    const int* dst0 = edges + E_;

    // --- mode select from ws_size (deterministic; graph-capture safe) ------
    const size_t R0 = 33554432ull, TAIL = 4194304ull;
    const size_t UVSZ = 104857600ull;           // 32768*1600*2
    const size_t P1SZ = 26214400ull;            // per-batch p1
    int CB = 0;
    if      (ws_size >= R0 + UVSZ + TAIL + 4 * P1SZ) CB = 4;
    else if (ws_size >= R0 + UVSZ + TAIL + 2 * P1SZ) CB = 2;
    const bool big = (CB >= 2);

    u16 *enc1, *whb, *p1, *p2, *featb16, *uv, *w1t, *w2t, *gwt, *uvwt, *hw2t;
    u16 *patchb16, *encb16;
    float *a_s, *a_d, *part; int *deg;
    if (big) {
        enc1    = (u16*)ws;
        featb16 = (u16*)ws;                     // overlays enc1 (dead)
        part    = (float*)ws;                   // head-phase reuse (featb16 dead)
        whb     = (u16*)(ws + R0);
        uv      = (u16*)(ws + R0);              // overlays whb (dead after gat)
        encb16  = (u16*)(ws + R0 + 26214400ull);// enc bf16, dead before UV GEMM
        p1      = (u16*)(ws + R0 + UVSZ);
        patchb16= (u16*)(ws + R0 + UVSZ);       // overlays p1 (dead before head)
        p2      = nullptr;
        size_t tb = (ws_size - TAIL) & ~(size_t)255;
        w1t  = (u16*)(ws + tb);
        w2t  = (u16*)(ws + tb + 786432);
        gwt  = (u16*)(ws + tb + 1196032);
        uvwt = (u16*)(ws + tb + 1516032);       // 1600*400*2 = 1,280,000
        hw2t = (u16*)(ws + tb + 2796032);
        a_s  = (float*)(ws + tb + 3436032);
        a_d  = (float*)(ws + tb + 3698176);
        deg  = (int*)(ws + tb + 3960320);
    } else {
        enc1    = (u16*)ws;                     // sequenced overlays
        whb     = (u16*)ws;
        p1      = (u16*)ws;
        featb16 = nullptr;
        patchb16= nullptr;
        encb16  = nullptr;
        part    = nullptr;
        p2      = (u16*)(ws + 26214400);
        uv      = (u16*)(ws + 39321600);        // 1024*1600*2 = 3,276,800
        w1t  = (u16*)(ws + 42598400);
        w2t  = (u16*)(ws + 43384832);
        gwt  = (u16*)(ws + 43794432);
        uvwt = (u16*)(ws + 44114432);
        hw2t = (u16*)(ws + 45394432);
        a_s  = (float*)(ws + 46034432);
        a_d  = (float*)(ws + 46296576);
        deg  = (int*)(ws + 46558720);
    }
    int* row_ptr = deg + 1024;
    int* cnt     = row_ptr + 1032;
    int* col_src = cnt + 1024;
    u16* zbuf = (u16*)(col_src + 17408);        // 256 B zero scratch (16B aligned)

    hipMemsetAsync(zbuf, 0, 256, stream);

    // weight transposes (bf16), tiny
    wt_k<<<(HID * IN_DIM + 255) / 256, 256, 0, stream>>>(enc_w1, w1t, IN_DIM, HID);
    wt_k<<<(OUT_ * HID + 255) / 256, 256, 0, stream>>>(enc_w2, w2t, HID, OUT_);
    wt_k<<<(OUT_ * OUT_ + 255) / 256, 256, 0, stream>>>(gat_w, gwt, OUT_, OUT_);
    wtuv_k<<<(UVW_ * OUT_ + 255) / 256, 256, 0, stream>>>(h_w1, uvwt);
    wt_k<<<(OUT_ * PAIR_ + 255) / 256, 256, 0, stream>>>(h_w2, hw2t, PAIR_, OUT_);

    // CSR by dst (batch-independent)
    hipMemsetAsync(deg, 0, 1024 * sizeof(int), stream);
    csr_count_k<<<(ET_ + 255) / 256, 256, 0, stream>>>(edges, deg);
    csr_scan_k<<<1, 1024, 0, stream>>>(deg, row_ptr, cnt);
    csr_fill_k<<<(ET_ + 255) / 256, 256, 0, stream>>>(edges, cnt, col_src);

    if (big) {
        // patch -> bf16 once (numerics identical: staging already cvt'd)
        f2b_k<<<(B_ * N_ * IN_DIM / 8 + 255) / 256, 256, 0, stream>>>(
            patch, patchb16, B_ * N_ * IN_DIM / 8);
        // encoder: enc1 = gelu(patch @ w1 + b1)   [wide 256x256]
        mfma_gemm_k<1, true, true, false, false, true><<<dim3(2, (B_ * N_) / 256), 512, 0, stream>>>(
            nullptr, patchb16, w1t, enc_b1, enc1, nullptr, B_ * N_, HID, IN_DIM, zbuf,
            nullptr, nullptr);
        // feat(f32, d_out) + encb16(bf16) = enc1 @ w2 + b2
        mfma_gemm_k<1, false, true, true, false, true><<<dim3(2, (B_ * N_) / 256), 512, 0, stream>>>(
            nullptr, enc1, w2t, enc_b2, encb16, feat, B_ * N_, OUT_, HID, zbuf,
            nullptr, nullptr);
        // GAT linear: wh = enc(bf16) @ gat_w
        mfma_gemm_k<1, false, false, false, false, true><<<dim3(2, (B_ * N_) / 256), 512, 0, stream>>>(
            nullptr, encb16, gwt, nullptr, whb, nullptr, B_ * N_, OUT_, OUT_, zbuf,
            nullptr, nullptr);
    } else {
        mfma_gemm_k<0, true, true, false, false, false><<<dim3(HID / 128, (B_ * N_) / 128), 256, 0, stream>>>(
            patch, nullptr, w1t, enc_b1, enc1, nullptr, B_ * N_, HID, IN_DIM, zbuf,
            nullptr, nullptr);
        mfma_gemm_k<1, false, true, true, false, false><<<dim3((OUT_ + 127) / 128, (B_ * N_) / 128), 256, 0, stream>>>(
            nullptr, enc1, w2t, enc_b2, nullptr, feat, B_ * N_, OUT_, HID, zbuf,
            nullptr, nullptr);
        mfma_gemm_k<0, false, false, false, false, false><<<dim3((OUT_ + 127) / 128, (B_ * N_) / 128), 256, 0, stream>>>(
            feat, nullptr, gwt, nullptr, whb, nullptr, B_ * N_, OUT_, OUT_, zbuf,
            nullptr, nullptr);
    }

    scores_k<<<(B_ * N_) / 4, 256, 0, stream>>>(whb, att_s, att_d, a_s, a_d);
    gat_k<<<B_ * N_, 256, 0, stream>>>(whb, a_s, a_d, row_ptr, col_src,
                                       gat_b, feat, featb16);

    // predict head — GEMM1 distributed (UV), GEMM2 wide-fused with head3.
    if (big) {
        // UV = featb16 @ uvwt  -> bf16 [32768,1600]   [wide: 7 col-tiles]
        mfma_gemm_k<1, false, false, false, false, true><<<dim3((UVW_ + 255) / 256, (B_ * N_) / 256), 512, 0, stream>>>(
            nullptr, featb16, uvwt, nullptr, uv, nullptr, B_ * N_, UVW_, OUT_, zbuf,
            nullptr, nullptr);
        for (int b0 = 0; b0 < B_; b0 += CB) {
            int Mr = CB * E_;
            pair_fuse_k<<<(Mr * 100 + 255) / 256, 256, 0, stream>>>(
                uv, h_b1, src0, dst0, p1, b0, Mr);
            mfma_gemm_k<1, true, true, false, true, true><<<dim3((OUT_ + 255) / 256, Mr / 256), 512, 0, stream>>>(
                nullptr, p1, hw2t, h_b2, nullptr, nullptr, Mr, OUT_, PAIR_, zbuf,
                h_w3, part);
            red3_k<<<(Mr + 255) / 256, 256, 0, stream>>>(part, h_b3, out, b0 * E_, Mr,
                                                         (OUT_ + 255) / 256);
        }
    } else {
        for (int b = 0; b < B_; ++b) {
            const float* featb = feat + (size_t)b * N_ * OUT_;
            mfma_gemm_k<0, false, false, false, false, false><<<dim3((UVW_ + 127) / 128, N_ / 128), 256, 0, stream>>>(
                featb, nullptr, uvwt, nullptr, uv, nullptr, N_, UVW_, OUT_, zbuf,
                nullptr, nullptr);
            pair_fuse_k<<<(E_ * 100 + 255) / 256, 256, 0, stream>>>(
                uv, h_b1, src0, dst0, p1, -1, E_);
            mfma_gemm_k<1, true, true, false, false, false><<<dim3((OUT_ + 127) / 128, E_ / 128), 256, 0, stream>>>(
                nullptr, p1, hw2t, h_b2, p2, nullptr, E_, OUT_, PAIR_, zbuf,
                nullptr, nullptr);
            head3_k<<<(E_ + 15) / 16, 256, 0, stream>>>(p2, h_w3, h_b3, out,
                                                        b * E_, E_);
        }
    }
}